// Round 2
// baseline (271.085 us; speedup 1.0000x reference)
//
#include <hip/hip_runtime.h>
#include <stdint.h>

#define DM    768
#define NH    12
#define HD    64
#define BATCH 4
#define SEQ   2048
#define NTOK  (BATCH*SEQ)   // 8192

typedef unsigned int   u32;
typedef unsigned short u16;
using bf16x8 = __attribute__((ext_vector_type(8))) short;
using f32x4  = __attribute__((ext_vector_type(4))) float;

__device__ __forceinline__ u16 f2bf(float f) {
    u32 u = __float_as_uint(f);
    u = (u + 0x7FFFu + ((u >> 16) & 1u)) >> 16;
    return (u16)u;
}

__device__ __forceinline__ void gload_lds16(const void* gptr, void* ldsptr) {
    __builtin_amdgcn_global_load_lds(
        (__attribute__((address_space(1))) const u32*)gptr,
        (__attribute__((address_space(3))) u32*)ldsptr, 16, 0, 0);
}

// ---------------- x fp32 -> bf16 (vectorized) ----------------
__global__ void cvt_x(const float* __restrict__ x, u16* __restrict__ xb, int n4) {
    int i = blockIdx.x * blockDim.x + threadIdx.x;
    if (i >= n4) return;
    float4 v = ((const float4*)x)[i];
    ushort4 o;
    o.x = f2bf(v.x); o.y = f2bf(v.y); o.z = f2bf(v.z); o.w = f2bf(v.w);
    ((ushort4*)xb)[i] = o;
}

// ------------- W [k][n] fp32 -> Wt [n][k] bf16 (tiled transpose) -------------
__global__ void transpose_w(const float* __restrict__ W, u16* __restrict__ Wt) {
    __shared__ float tile[32][33];
    int tx = threadIdx.x, ty = threadIdx.y;   // 32 x 8
    int x0 = blockIdx.x * 32, y0 = blockIdx.y * 32;
    #pragma unroll
    for (int i = 0; i < 32; i += 8)
        tile[ty + i][tx] = W[(size_t)(y0 + ty + i) * DM + x0 + tx];
    __syncthreads();
    #pragma unroll
    for (int i = 0; i < 32; i += 8)
        Wt[(size_t)(x0 + ty + i) * DM + y0 + tx] = f2bf(tile[tx][ty + i]);
}

// ---------------- 128x128 bf16 MFMA GEMM (m97-style structure) ----------------
// MODE 0: A=xb[8192][768], Bt=Wqkv^T[2304][768] -> scatter Q(scaled)/K [BH][S][64], V^T [BH][64][S]
// MODE 1: A=ctx[8192][768], Bt=Wo^T[768][768]   -> Out fp32 [8192][768] + bias
template <int MODE>
__global__ __launch_bounds__(256)
void gemm128(const u16* __restrict__ A, const u16* __restrict__ Bt,
             const float* __restrict__ b0, const float* __restrict__ b1,
             const float* __restrict__ b2,
             u16* __restrict__ Qo, u16* __restrict__ Ko, u16* __restrict__ Vto,
             float* __restrict__ Out)
{
    __shared__ u16 As[128][32];
    __shared__ u16 Bs[128][32];
    const int t = threadIdx.x;
    const int w = t >> 6, l = t & 63;
    const int l15 = l & 15, lg = l >> 4;
    const int m0 = blockIdx.x * 128;
    const int n0 = blockIdx.y * 128;
    const int wr = (w >> 1) * 64, wc = (w & 1) * 64;

    f32x4 zf = {0.f, 0.f, 0.f, 0.f};
    f32x4 acc[4][4];
    #pragma unroll
    for (int i = 0; i < 4; ++i)
        #pragma unroll
        for (int j = 0; j < 4; ++j) acc[i][j] = zf;

    const u16* Arow0 = A  + (size_t)m0 * DM;
    const u16* Brow0 = Bt + (size_t)n0 * DM;

    for (int k0 = 0; k0 < DM; k0 += 32) {
        #pragma unroll
        for (int p = 0; p < 2; ++p) {
            int f = p * 256 + t;
            int row = f >> 2, c8 = (f & 3) * 8;
            gload_lds16(Arow0 + (size_t)row * DM + k0 + c8, &As[row][c8]);
            gload_lds16(Brow0 + (size_t)row * DM + k0 + c8, &Bs[row][c8]);
        }
        __syncthreads();
        bf16x8 af[4], bfr[4];
        #pragma unroll
        for (int m = 0; m < 4; ++m)
            af[m] = *(const bf16x8*)&As[wr + m * 16 + l15][lg * 8];
        #pragma unroll
        for (int n = 0; n < 4; ++n)
            bfr[n] = *(const bf16x8*)&Bs[wc + n * 16 + l15][lg * 8];
        #pragma unroll
        for (int m = 0; m < 4; ++m)
            #pragma unroll
            for (int n = 0; n < 4; ++n)
                acc[m][n] = __builtin_amdgcn_mfma_f32_16x16x32_bf16(af[m], bfr[n], acc[m][n], 0, 0, 0);
        __syncthreads();
    }

    if (MODE == 1) {
        #pragma unroll
        for (int m = 0; m < 4; ++m) {
            int grow = m0 + wr + m * 16 + lg * 4;
            #pragma unroll
            for (int n = 0; n < 4; ++n) {
                int gcol = n0 + wc + n * 16 + l15;
                float bias = b0[gcol];
                #pragma unroll
                for (int r = 0; r < 4; ++r)
                    Out[(size_t)(grow + r) * DM + gcol] = acc[m][n][r] + bias;
            }
        }
    } else {
        #pragma unroll
        for (int m = 0; m < 4; ++m) {
            int grow = m0 + wr + m * 16 + lg * 4;
            #pragma unroll
            for (int n = 0; n < 4; ++n) {
                int gcol = n0 + wc + n * 16 + l15;
                int which = gcol / DM;
                int c = gcol - which * DM;
                int h = c >> 6, hd = c & 63;
                const float* bp = (which == 0) ? b0 : (which == 1) ? b1 : b2;
                float bias = bp[c];
                #pragma unroll
                for (int r = 0; r < 4; ++r) {
                    int M = grow + r;
                    int bb = M >> 11, ss = M & 2047;
                    float v = acc[m][n][r] + bias;
                    if (which == 0)
                        Qo[(((size_t)bb * NH + h) * SEQ + ss) * HD + hd] = f2bf(v * 0.125f);
                    else if (which == 1)
                        Ko[(((size_t)bb * NH + h) * SEQ + ss) * HD + hd] = f2bf(v);
                    else
                        Vto[(((size_t)bb * NH + h) * HD + hd) * SEQ + ss] = f2bf(v);
                }
            }
        }
    }
}

// ---------------- causal flash attention ----------------
// Q pre-scaled by 1/8. Q,K: [BH][S][64] bf16. Vt: [BH][64][S] bf16.
// Block: 64 q-rows (4 waves x 16 rows). KV tile = 64.
__global__ __launch_bounds__(256)
void attn_fwd(const u16* __restrict__ Q, const u16* __restrict__ K_,
              const u16* __restrict__ Vt, u16* __restrict__ ctx)
{
    __shared__ u16 Ks[64][72];      // +8 pad: kills stride-128B bank conflict
    __shared__ u16 Vs[64][72];
    __shared__ u16 Ps[4][16][72];

    const int t = threadIdx.x, w = t >> 6, l = t & 63;
    const int l15 = l & 15, lg = l >> 4;
    const int qi = blockIdx.x & 31;
    const int bh = blockIdx.x >> 5;
    const int b = bh / NH, h = bh - b * NH;
    const int wrow0 = qi * 64 + w * 16;

    // Q fragments (held in regs for the whole block)
    const u16* Qp = Q + ((size_t)bh * SEQ + wrow0 + l15) * HD;
    bf16x8 qf[2];
    qf[0] = *(const bf16x8*)(Qp + lg * 8);
    qf[1] = *(const bf16x8*)(Qp + 32 + lg * 8);

    f32x4 zf = {0.f, 0.f, 0.f, 0.f};
    f32x4 acc_o[4];
    #pragma unroll
    for (int d = 0; d < 4; ++d) acc_o[d] = zf;
    float mi[4], li[4];
    #pragma unroll
    for (int r = 0; r < 4; ++r) { mi[r] = -INFINITY; li[r] = 0.f; }

    const u16* Kbh = K_ + (size_t)bh * SEQ * HD;
    const u16* Vbh = Vt + (size_t)bh * HD * SEQ;

    for (int j0 = 0; j0 <= qi * 64; j0 += 64) {
        // stage K tile [64][64] and V^T tile [64][64]
        // 64x64 u16 = 512 int4 chunks; 256 threads x 2 chunks each (FULL coverage)
        #pragma unroll
        for (int i = 0; i < 2; ++i) {
            int f = i * 256 + t;
            int row = f >> 3, c8 = (f & 7) * 8;
            *(int4*)&Ks[row][c8] = *(const int4*)(Kbh + (size_t)(j0 + row) * HD + c8);
            *(int4*)&Vs[row][c8] = *(const int4*)(Vbh + (size_t)row * SEQ + j0 + c8);
        }
        __syncthreads();

        if (j0 <= wrow0 + 15) {   // wave has at least one unmasked row in this tile
            // S = Q K^T  (16 x 64 per wave)
            f32x4 sc[4];
            #pragma unroll
            for (int nt = 0; nt < 4; ++nt) {
                bf16x8 kf0 = *(const bf16x8*)&Ks[nt * 16 + l15][lg * 8];
                bf16x8 kf1 = *(const bf16x8*)&Ks[nt * 16 + l15][32 + lg * 8];
                f32x4 a = zf;
                a = __builtin_amdgcn_mfma_f32_16x16x32_bf16(qf[0], kf0, a, 0, 0, 0);
                a = __builtin_amdgcn_mfma_f32_16x16x32_bf16(qf[1], kf1, a, 0, 0, 0);
                sc[nt] = a;
            }
            if (j0 + 63 > wrow0) {   // partial tile: per-element causal mask
                #pragma unroll
                for (int nt = 0; nt < 4; ++nt) {
                    int ng = j0 + nt * 16 + l15;
                    #pragma unroll
                    for (int r = 0; r < 4; ++r)
                        if (ng > wrow0 + lg * 4 + r) sc[nt][r] = -INFINITY;
                }
            }
            // online softmax (row stats across 16-lane groups)
            float cm[4];
            #pragma unroll
            for (int r = 0; r < 4; ++r)
                cm[r] = fmaxf(fmaxf(sc[0][r], sc[1][r]), fmaxf(sc[2][r], sc[3][r]));
            #pragma unroll
            for (int r = 0; r < 4; ++r) {
                cm[r] = fmaxf(cm[r], __shfl_xor(cm[r], 1));
                cm[r] = fmaxf(cm[r], __shfl_xor(cm[r], 2));
                cm[r] = fmaxf(cm[r], __shfl_xor(cm[r], 4));
                cm[r] = fmaxf(cm[r], __shfl_xor(cm[r], 8));
            }
            float so[4], rs[4];
            #pragma unroll
            for (int r = 0; r < 4; ++r) {
                float mn = fmaxf(mi[r], cm[r]);
                so[r] = __expf(mi[r] - mn);   // first tile: exp(-inf)=0
                mi[r] = mn;
                rs[r] = 0.f;
            }
            #pragma unroll
            for (int nt = 0; nt < 4; ++nt)
                #pragma unroll
                for (int r = 0; r < 4; ++r) {
                    float p = __expf(sc[nt][r] - mi[r]);
                    rs[r] += p;
                    Ps[w][lg * 4 + r][nt * 16 + l15] = f2bf(p);
                }
            #pragma unroll
            for (int r = 0; r < 4; ++r) {
                rs[r] += __shfl_xor(rs[r], 1);
                rs[r] += __shfl_xor(rs[r], 2);
                rs[r] += __shfl_xor(rs[r], 4);
                rs[r] += __shfl_xor(rs[r], 8);
                li[r] = li[r] * so[r] + rs[r];
            }
            #pragma unroll
            for (int d = 0; d < 4; ++d)
                #pragma unroll
                for (int r = 0; r < 4; ++r) acc_o[d][r] *= so[r];
            // O += P V   (A = P row-major from LDS, B = V^T rows)
            bf16x8 pa0 = *(const bf16x8*)&Ps[w][l15][lg * 8];
            bf16x8 pa1 = *(const bf16x8*)&Ps[w][l15][32 + lg * 8];
            #pragma unroll
            for (int d = 0; d < 4; ++d) {
                bf16x8 vf0 = *(const bf16x8*)&Vs[d * 16 + l15][lg * 8];
                bf16x8 vf1 = *(const bf16x8*)&Vs[d * 16 + l15][32 + lg * 8];
                acc_o[d] = __builtin_amdgcn_mfma_f32_16x16x32_bf16(pa0, vf0, acc_o[d], 0, 0, 0);
                acc_o[d] = __builtin_amdgcn_mfma_f32_16x16x32_bf16(pa1, vf1, acc_o[d], 0, 0, 0);
            }
        }
        __syncthreads();
    }

    // epilogue: ctx [B][S][768] bf16
    #pragma unroll
    for (int r = 0; r < 4; ++r) {
        float inv = 1.0f / li[r];
        int s = wrow0 + lg * 4 + r;
        size_t base = ((size_t)b * SEQ + s) * DM + h * HD;
        #pragma unroll
        for (int d = 0; d < 4; ++d)
            ctx[base + d * 16 + l15] = f2bf(acc_o[d][r] * inv);
    }
}

extern "C" void kernel_launch(void* const* d_in, const int* in_sizes, int n_in,
                              void* d_out, int out_size, void* d_ws, size_t ws_size,
                              hipStream_t stream) {
    const float* x  = (const float*)d_in[0];
    const float* Wq = (const float*)d_in[1];
    const float* bq = (const float*)d_in[2];
    const float* Wk = (const float*)d_in[3];
    const float* bk = (const float*)d_in[4];
    const float* Wv = (const float*)d_in[5];
    const float* bv = (const float*)d_in[6];
    const float* Wo = (const float*)d_in[7];
    const float* bo = (const float*)d_in[8];
    float* out = (float*)d_out;

    char* ws = (char*)d_ws;
    u16* xb  = (u16*)(ws);                    // 8192*768*2      = 12,582,912
    u16* Wt  = (u16*)(ws + 12582912);         // 2304*768*2      =  3,538,944
    u16* Wto = (u16*)(ws + 16121856);         // 768*768*2       =  1,179,648
    u16* Qw  = (u16*)(ws + 17301504);         // [BH][S][64]     = 12,582,912
    u16* Kw  = (u16*)(ws + 29884416);         // [BH][S][64]     = 12,582,912
    u16* Vtw = (u16*)(ws + 42467328);         // [BH][64][S]     = 12,582,912
    u16* ctx = (u16*)(ws + 55050240);         // [B][S][768]     = 12,582,912

    cvt_x<<<6144, 256, 0, stream>>>(x, xb, NTOK * DM / 4);
    dim3 tb(32, 8), tg(24, 24);
    transpose_w<<<tg, tb, 0, stream>>>(Wq, Wt);
    transpose_w<<<tg, tb, 0, stream>>>(Wk, Wt + 768 * 768);
    transpose_w<<<tg, tb, 0, stream>>>(Wv, Wt + 2 * 768 * 768);
    transpose_w<<<tg, tb, 0, stream>>>(Wo, Wto);

    dim3 g2(64, 18);
    gemm128<0><<<g2, 256, 0, stream>>>(xb, Wt, bq, bk, bv, Qw, Kw, Vtw, nullptr);
    attn_fwd<<<1536, 256, 0, stream>>>(Qw, Kw, Vtw, ctx);
    dim3 g4(64, 6);
    gemm128<1><<<g4, 256, 0, stream>>>(ctx, Wto, bo, nullptr, nullptr, nullptr, nullptr, nullptr, out);
}

// Round 3
// 173.018 us; speedup vs baseline: 1.5668x; 1.5668x over previous
//
#include <hip/hip_runtime.h>
#include <stdint.h>

#define DM    768
#define NH    12
#define HD    64
#define BATCH 4
#define SEQ   2048
#define NTOK  (BATCH*SEQ)   // 8192

typedef unsigned int   u32;
typedef unsigned short u16;
using bf16x8 = __attribute__((ext_vector_type(8))) short;
using f32x4  = __attribute__((ext_vector_type(4))) float;

__device__ __forceinline__ u16 f2bf(float f) {
    u32 u = __float_as_uint(f);
    u = (u + 0x7FFFu + ((u >> 16) & 1u)) >> 16;
    return (u16)u;
}

__device__ __forceinline__ u32 pkbf(float a, float b) {
    u32 r;
    asm("v_cvt_pk_bf16_f32 %0, %1, %2" : "=v"(r) : "v"(a), "v"(b));
    return r;
}

__device__ __forceinline__ void gload_lds16(const void* gptr, void* ldsptr) {
    __builtin_amdgcn_global_load_lds(
        (__attribute__((address_space(1))) const u32*)gptr,
        (__attribute__((address_space(3))) u32*)ldsptr, 16, 0, 0);
}

// ---------------- x fp32 -> bf16 (vectorized) ----------------
__global__ void cvt_x(const float* __restrict__ x, u16* __restrict__ xb, int n4) {
    int i = blockIdx.x * blockDim.x + threadIdx.x;
    if (i >= n4) return;
    float4 v = ((const float4*)x)[i];
    ushort4 o;
    o.x = f2bf(v.x); o.y = f2bf(v.y); o.z = f2bf(v.z); o.w = f2bf(v.w);
    ((ushort4*)xb)[i] = o;
}

// ------------- W [k][n] fp32 -> Wt [n][k] bf16 (tiled transpose) -------------
__global__ void transpose_w(const float* __restrict__ W, u16* __restrict__ Wt) {
    __shared__ float tile[32][33];
    int tx = threadIdx.x, ty = threadIdx.y;   // 32 x 8
    int x0 = blockIdx.x * 32, y0 = blockIdx.y * 32;
    #pragma unroll
    for (int i = 0; i < 32; i += 8)
        tile[ty + i][tx] = W[(size_t)(y0 + ty + i) * DM + x0 + tx];
    __syncthreads();
    #pragma unroll
    for (int i = 0; i < 32; i += 8)
        Wt[(size_t)(x0 + ty + i) * DM + y0 + tx] = f2bf(tile[tx][ty + i]);
}

// ---------------- 128x128 bf16 MFMA GEMM (m97-style structure) ----------------
template <int MODE>
__global__ __launch_bounds__(256)
void gemm128(const u16* __restrict__ A, const u16* __restrict__ Bt,
             const float* __restrict__ b0, const float* __restrict__ b1,
             const float* __restrict__ b2,
             u16* __restrict__ Qo, u16* __restrict__ Ko, u16* __restrict__ Vto,
             float* __restrict__ Out)
{
    __shared__ u16 As[128][32];
    __shared__ u16 Bs[128][32];
    const int t = threadIdx.x;
    const int w = t >> 6, l = t & 63;
    const int l15 = l & 15, lg = l >> 4;
    const int m0 = blockIdx.x * 128;
    const int n0 = blockIdx.y * 128;
    const int wr = (w >> 1) * 64, wc = (w & 1) * 64;

    f32x4 zf = {0.f, 0.f, 0.f, 0.f};
    f32x4 acc[4][4];
    #pragma unroll
    for (int i = 0; i < 4; ++i)
        #pragma unroll
        for (int j = 0; j < 4; ++j) acc[i][j] = zf;

    const u16* Arow0 = A  + (size_t)m0 * DM;
    const u16* Brow0 = Bt + (size_t)n0 * DM;

    for (int k0 = 0; k0 < DM; k0 += 32) {
        #pragma unroll
        for (int p = 0; p < 2; ++p) {
            int f = p * 256 + t;
            int row = f >> 2, c8 = (f & 3) * 8;
            gload_lds16(Arow0 + (size_t)row * DM + k0 + c8, &As[row][c8]);
            gload_lds16(Brow0 + (size_t)row * DM + k0 + c8, &Bs[row][c8]);
        }
        __syncthreads();
        bf16x8 af[4], bfr[4];
        #pragma unroll
        for (int m = 0; m < 4; ++m)
            af[m] = *(const bf16x8*)&As[wr + m * 16 + l15][lg * 8];
        #pragma unroll
        for (int n = 0; n < 4; ++n)
            bfr[n] = *(const bf16x8*)&Bs[wc + n * 16 + l15][lg * 8];
        #pragma unroll
        for (int m = 0; m < 4; ++m)
            #pragma unroll
            for (int n = 0; n < 4; ++n)
                acc[m][n] = __builtin_amdgcn_mfma_f32_16x16x32_bf16(af[m], bfr[n], acc[m][n], 0, 0, 0);
        __syncthreads();
    }

    if (MODE == 1) {
        #pragma unroll
        for (int m = 0; m < 4; ++m) {
            int grow = m0 + wr + m * 16 + lg * 4;
            #pragma unroll
            for (int n = 0; n < 4; ++n) {
                int gcol = n0 + wc + n * 16 + l15;
                float bias = b0[gcol];
                #pragma unroll
                for (int r = 0; r < 4; ++r)
                    Out[(size_t)(grow + r) * DM + gcol] = acc[m][n][r] + bias;
            }
        }
    } else {
        #pragma unroll
        for (int m = 0; m < 4; ++m) {
            int grow = m0 + wr + m * 16 + lg * 4;
            #pragma unroll
            for (int n = 0; n < 4; ++n) {
                int gcol = n0 + wc + n * 16 + l15;
                int which = gcol / DM;
                int c = gcol - which * DM;
                int h = c >> 6, hd = c & 63;
                const float* bp = (which == 0) ? b0 : (which == 1) ? b1 : b2;
                float bias = bp[c];
                #pragma unroll
                for (int r = 0; r < 4; ++r) {
                    int M = grow + r;
                    int bb = M >> 11, ss = M & 2047;
                    float v = acc[m][n][r] + bias;
                    if (which == 0)
                        Qo[(((size_t)bb * NH + h) * SEQ + ss) * HD + hd] = f2bf(v * 0.125f);
                    else if (which == 1)
                        Ko[(((size_t)bb * NH + h) * SEQ + ss) * HD + hd] = f2bf(v);
                    else
                        Vto[(((size_t)bb * NH + h) * HD + hd) * SEQ + ss] = f2bf(v);
                }
            }
        }
    }
}

// ---------------- causal flash attention v2 ----------------
// 8 waves x 16 rows = 128 Q rows per block. KV tile = 64, double-buffered,
// issue-early/write-late. Swapped QK^T (mfma(K,Q)) => softmax axis lane-local,
// P stays in registers (k-slot permutation shared with the V fragment reads).
__global__ __launch_bounds__(512, 4)
void attn_fwd(const u16* __restrict__ Q, const u16* __restrict__ K_,
              const u16* __restrict__ Vt, u16* __restrict__ ctx)
{
    __shared__ u16 Ks[2][64][72];
    __shared__ u16 Vs[2][64][72];

    const int t = threadIdx.x, w = t >> 6, l = t & 63;
    const int l15 = l & 15, lg = l >> 4;
    const int bx = blockIdx.x;
    const int ord = bx / 48;            // ascending => qblk descending (LPT dispatch)
    const int bh  = bx - ord * 48;
    const int qblk = 15 - ord;
    const int b = bh / NH, h = bh - b * NH;
    const int wrow0 = qblk * 128 + w * 16;
    const int jmax = 2 * qblk + 1;

    // Q fragments (B-operand of swapped QK^T: lane l15 = q row)
    const u16* Qp = Q + ((size_t)bh * SEQ + wrow0 + l15) * HD;
    bf16x8 qf0 = *(const bf16x8*)(Qp + lg * 8);
    bf16x8 qf1 = *(const bf16x8*)(Qp + 32 + lg * 8);

    f32x4 zf = {0.f, 0.f, 0.f, 0.f};
    f32x4 acc[4];
    #pragma unroll
    for (int d = 0; d < 4; ++d) acc[d] = zf;
    float mi = -INFINITY, li = 0.f;     // stats for q = wrow0 + l15 (replicated over lg)

    const u16* Kbh = K_ + (size_t)bh * SEQ * HD;
    const u16* Vbh = Vt + (size_t)bh * HD * SEQ;
    const int row = t >> 3, c8 = (t & 7) * 8;   // 512 thr x 1 int4 = full 64x64 tile

    // prologue: stage tile 0
    {
        int4 kr = *(const int4*)(Kbh + (size_t)row * HD + c8);
        int4 vr = *(const int4*)(Vbh + (size_t)row * SEQ + c8);
        *(int4*)&Ks[0][row][c8] = kr;
        *(int4*)&Vs[0][row][c8] = vr;
    }
    __syncthreads();

    for (int jt = 0; jt <= jmax; ++jt) {
        const int cur = jt & 1;
        const int j0 = jt << 6;
        int4 kn, vn;
        if (jt < jmax) {    // issue next-tile loads early (latency hides under compute)
            int j1 = j0 + 64;
            kn = *(const int4*)(Kbh + (size_t)(j1 + row) * HD + c8);
            vn = *(const int4*)(Vbh + (size_t)row * SEQ + j1 + c8);
        }
        if (j0 <= wrow0 + 15) {     // wave-uniform causal skip
            const u16 (*Kc)[72] = Ks[cur];
            const u16 (*Vc)[72] = Vs[cur];
            // S^T tile: rows = keys (lg*4+r), cols = q (l15)
            f32x4 sc[4];
            #pragma unroll
            for (int nt = 0; nt < 4; ++nt) {
                bf16x8 kf0 = *(const bf16x8*)&Kc[nt * 16 + l15][lg * 8];
                bf16x8 kf1 = *(const bf16x8*)&Kc[nt * 16 + l15][32 + lg * 8];
                f32x4 a = zf;
                a = __builtin_amdgcn_mfma_f32_16x16x32_bf16(kf0, qf0, a, 0, 0, 0);
                a = __builtin_amdgcn_mfma_f32_16x16x32_bf16(kf1, qf1, a, 0, 0, 0);
                sc[nt] = a;
            }
            if (j0 + 63 > wrow0) {  // diagonal tile: per-element causal mask
                #pragma unroll
                for (int nt = 0; nt < 4; ++nt) {
                    int kb = j0 + nt * 16 + lg * 4;
                    #pragma unroll
                    for (int r = 0; r < 4; ++r)
                        if (kb + r > wrow0 + l15) sc[nt][r] = -INFINITY;
                }
            }
            // online softmax: key axis is lane-local (16 regs) + 2 cross-lg shuffles
            float cm = sc[0][0];
            #pragma unroll
            for (int nt = 0; nt < 4; ++nt)
                #pragma unroll
                for (int r = 0; r < 4; ++r) cm = fmaxf(cm, sc[nt][r]);
            cm = fmaxf(cm, __shfl_xor(cm, 16));
            cm = fmaxf(cm, __shfl_xor(cm, 32));
            float mn = fmaxf(mi, cm);
            float so = __expf(mi - mn);
            mi = mn;
            float rs = 0.f;
            u32 dw0, dw1, dw2, dw3, dw4, dw5, dw6, dw7;
            {
                float p0, p1, p2, p3;
                p0 = __expf(sc[0][0] - mn); p1 = __expf(sc[0][1] - mn);
                p2 = __expf(sc[0][2] - mn); p3 = __expf(sc[0][3] - mn);
                rs += (p0 + p1) + (p2 + p3); dw0 = pkbf(p0, p1); dw1 = pkbf(p2, p3);
                p0 = __expf(sc[1][0] - mn); p1 = __expf(sc[1][1] - mn);
                p2 = __expf(sc[1][2] - mn); p3 = __expf(sc[1][3] - mn);
                rs += (p0 + p1) + (p2 + p3); dw2 = pkbf(p0, p1); dw3 = pkbf(p2, p3);
                p0 = __expf(sc[2][0] - mn); p1 = __expf(sc[2][1] - mn);
                p2 = __expf(sc[2][2] - mn); p3 = __expf(sc[2][3] - mn);
                rs += (p0 + p1) + (p2 + p3); dw4 = pkbf(p0, p1); dw5 = pkbf(p2, p3);
                p0 = __expf(sc[3][0] - mn); p1 = __expf(sc[3][1] - mn);
                p2 = __expf(sc[3][2] - mn); p3 = __expf(sc[3][3] - mn);
                rs += (p0 + p1) + (p2 + p3); dw6 = pkbf(p0, p1); dw7 = pkbf(p2, p3);
            }
            rs += __shfl_xor(rs, 16);
            rs += __shfl_xor(rs, 32);
            li = li * so + rs;
            // rescale O: acc rows are q = lg*4+r -> fetch that row's so
            float so0 = __shfl(so, lg * 4 + 0), so1 = __shfl(so, lg * 4 + 1);
            float so2 = __shfl(so, lg * 4 + 2), so3 = __shfl(so, lg * 4 + 3);
            #pragma unroll
            for (int d = 0; d < 4; ++d) {
                acc[d][0] *= so0; acc[d][1] *= so1;
                acc[d][2] *= so2; acc[d][3] *= so3;
            }
            // P fragments: lane's own 16 values, k-slot sigma(lg,j) = (2kk+h)*16+lg*4+r
            bf16x8 pa0 = __builtin_bit_cast(bf16x8, make_int4((int)dw0, (int)dw1, (int)dw2, (int)dw3));
            bf16x8 pa1 = __builtin_bit_cast(bf16x8, make_int4((int)dw4, (int)dw5, (int)dw6, (int)dw7));
            // O += P V  (V fragments read with the same k-slot permutation)
            #pragma unroll
            for (int d = 0; d < 4; ++d) {
                const u16* vrow = Vc[d * 16 + l15];
                int2 a0 = *(const int2*)(vrow + lg * 4);
                int2 a1 = *(const int2*)(vrow + 16 + lg * 4);
                int2 a2 = *(const int2*)(vrow + 32 + lg * 4);
                int2 a3 = *(const int2*)(vrow + 48 + lg * 4);
                bf16x8 vf0 = __builtin_bit_cast(bf16x8, make_int4(a0.x, a0.y, a1.x, a1.y));
                bf16x8 vf1 = __builtin_bit_cast(bf16x8, make_int4(a2.x, a2.y, a3.x, a3.y));
                acc[d] = __builtin_amdgcn_mfma_f32_16x16x32_bf16(pa0, vf0, acc[d], 0, 0, 0);
                acc[d] = __builtin_amdgcn_mfma_f32_16x16x32_bf16(pa1, vf1, acc[d], 0, 0, 0);
            }
        }
        if (jt < jmax) {    // write-late into the other buffer (safe: no readers)
            *(int4*)&Ks[cur ^ 1][row][c8] = kn;
            *(int4*)&Vs[cur ^ 1][row][c8] = vn;
        }
        __syncthreads();
    }

    // epilogue: ctx [B][S][768] bf16; acc rows = q (lg*4+r), cols = d (l15)
    float il0 = 1.0f / __shfl(li, lg * 4 + 0);
    float il1 = 1.0f / __shfl(li, lg * 4 + 1);
    float il2 = 1.0f / __shfl(li, lg * 4 + 2);
    float il3 = 1.0f / __shfl(li, lg * 4 + 3);
    #pragma unroll
    for (int r = 0; r < 4; ++r) {
        float il = (r == 0) ? il0 : (r == 1) ? il1 : (r == 2) ? il2 : il3;
        int s = wrow0 + lg * 4 + r;
        size_t base = ((size_t)b * SEQ + s) * DM + h * HD;
        #pragma unroll
        for (int d = 0; d < 4; ++d)
            ctx[base + d * 16 + l15] = f2bf(acc[d][r] * il);
    }
}

extern "C" void kernel_launch(void* const* d_in, const int* in_sizes, int n_in,
                              void* d_out, int out_size, void* d_ws, size_t ws_size,
                              hipStream_t stream) {
    const float* x  = (const float*)d_in[0];
    const float* Wq = (const float*)d_in[1];
    const float* bq = (const float*)d_in[2];
    const float* Wk = (const float*)d_in[3];
    const float* bk = (const float*)d_in[4];
    const float* Wv = (const float*)d_in[5];
    const float* bv = (const float*)d_in[6];
    const float* Wo = (const float*)d_in[7];
    const float* bo = (const float*)d_in[8];
    float* out = (float*)d_out;

    char* ws = (char*)d_ws;
    u16* xb  = (u16*)(ws);                    // 8192*768*2      = 12,582,912
    u16* Wt  = (u16*)(ws + 12582912);         // 2304*768*2      =  3,538,944
    u16* Wto = (u16*)(ws + 16121856);         // 768*768*2       =  1,179,648
    u16* Qw  = (u16*)(ws + 17301504);         // [BH][S][64]     = 12,582,912
    u16* Kw  = (u16*)(ws + 29884416);         // [BH][S][64]     = 12,582,912
    u16* Vtw = (u16*)(ws + 42467328);         // [BH][64][S]     = 12,582,912
    u16* ctx = (u16*)(ws + 55050240);         // [B][S][768]     = 12,582,912

    cvt_x<<<6144, 256, 0, stream>>>(x, xb, NTOK * DM / 4);
    dim3 tb(32, 8), tg(24, 24);
    transpose_w<<<tg, tb, 0, stream>>>(Wq, Wt);
    transpose_w<<<tg, tb, 0, stream>>>(Wk, Wt + 768 * 768);
    transpose_w<<<tg, tb, 0, stream>>>(Wv, Wt + 2 * 768 * 768);
    transpose_w<<<tg, tb, 0, stream>>>(Wo, Wto);

    dim3 g2(64, 18);
    gemm128<0><<<g2, 256, 0, stream>>>(xb, Wt, bq, bk, bv, Qw, Kw, Vtw, nullptr);
    attn_fwd<<<768, 512, 0, stream>>>(Qw, Kw, Vtw, ctx);
    dim3 g4(64, 6);
    gemm128<1><<<g4, 256, 0, stream>>>(ctx, Wto, bo, nullptr, nullptr, nullptr, nullptr, nullptr, out);
}

// Round 4
// 165.367 us; speedup vs baseline: 1.6393x; 1.0463x over previous
//
#include <hip/hip_runtime.h>
#include <stdint.h>

#define DM    768
#define NH    12
#define HD    64
#define BATCH 4
#define SEQ   2048
#define NTOK  (BATCH*SEQ)   // 8192
#define NSTEP 24            // 768 / 32

typedef unsigned int   u32;
typedef unsigned short u16;
using bf16x8 = __attribute__((ext_vector_type(8))) short;
using f32x4  = __attribute__((ext_vector_type(4))) float;

__device__ __forceinline__ u16 f2bf(float f) {
    u32 u = __float_as_uint(f);
    u = (u + 0x7FFFu + ((u >> 16) & 1u)) >> 16;
    return (u16)u;
}

__device__ __forceinline__ u32 pkbf(float a, float b) {
    u32 r;
    asm("v_cvt_pk_bf16_f32 %0, %1, %2" : "=v"(r) : "v"(a), "v"(b));
    return r;
}

__device__ __forceinline__ void gload_lds16(const void* gptr, void* ldsptr) {
    __builtin_amdgcn_global_load_lds(
        (__attribute__((address_space(1))) const u32*)gptr,
        (__attribute__((address_space(3))) u32*)ldsptr, 16, 0, 0);
}

// ---------------- x fp32 -> bf16 (vectorized) ----------------
__global__ void cvt_x(const float* __restrict__ x, u16* __restrict__ xb, int n4) {
    int i = blockIdx.x * blockDim.x + threadIdx.x;
    if (i >= n4) return;
    float4 v = ((const float4*)x)[i];
    ushort4 o;
    o.x = f2bf(v.x); o.y = f2bf(v.y); o.z = f2bf(v.z); o.w = f2bf(v.w);
    ((ushort4*)xb)[i] = o;
}

// ------- all 4 weight transposes in ONE launch: W [k][n] fp32 -> Wt [n][k] bf16 -------
__global__ void transpose_w4(const float* __restrict__ q, const float* __restrict__ k,
                             const float* __restrict__ v, const float* __restrict__ o,
                             u16* __restrict__ Wt, u16* __restrict__ Wto) {
    __shared__ float tile[32][33];
    int z = blockIdx.z;
    const float* W = (z == 0) ? q : (z == 1) ? k : (z == 2) ? v : o;
    u16* D = (z < 3) ? (Wt + (size_t)z * DM * DM) : Wto;
    int tx = threadIdx.x, ty = threadIdx.y;   // 32 x 8
    int x0 = blockIdx.x * 32, y0 = blockIdx.y * 32;
    #pragma unroll
    for (int i = 0; i < 32; i += 8)
        tile[ty + i][tx] = W[(size_t)(y0 + ty + i) * DM + x0 + tx];
    __syncthreads();
    #pragma unroll
    for (int i = 0; i < 32; i += 8)
        D[(size_t)(x0 + ty + i) * DM + y0 + tx] = f2bf(tile[tx][ty + i]);
}

// ------------- 256x128 bf16 MFMA GEMM, double-buffered 2-phase pipeline -------------
// 8 waves (512 thr), wave grid 4Mx2N, per-wave 64x64 output. BK=32.
// LDS XOR pre-swizzle on the global source (linear gload_lds dest, rule #21).
// MODE 0: A=xb[8192][768], Bt=Wqkv^T[2304][768] -> Q(scaled)/K [BH][S][64], V^T [BH][64][S]
// MODE 1: A=ctx[8192][768], Bt=Wo^T[768][768]   -> Out fp32 [8192][768] + bias
template <int MODE>
__global__ __launch_bounds__(512)
void gemm256(const u16* __restrict__ A, const u16* __restrict__ Bt,
             const float* __restrict__ b0, const float* __restrict__ b1,
             const float* __restrict__ b2,
             u16* __restrict__ Qo, u16* __restrict__ Ko, u16* __restrict__ Vto,
             float* __restrict__ Out)
{
    __shared__ u16 As[2][256][32];
    __shared__ u16 Bs[2][128][32];
    const int t = threadIdx.x;
    const int w = t >> 6, l = t & 63;
    const int l15 = l & 15, lg = l >> 4;
    const int slg = lg ^ ((l15 >> 1) & 3);          // de-swizzled read chunk
    const int m0 = blockIdx.x * 256;
    const int n0 = blockIdx.y * 128;
    const int wr = (w >> 1) * 64, wc = (w & 1) * 64;

    f32x4 zf = {0.f, 0.f, 0.f, 0.f};
    f32x4 acc[4][4];
    #pragma unroll
    for (int i = 0; i < 4; ++i)
        #pragma unroll
        for (int j = 0; j < 4; ++j) acc[i][j] = zf;

    const u16* Arow0 = A  + (size_t)m0 * DM;
    const u16* Brow0 = Bt + (size_t)n0 * DM;

    auto stage = [&](int d, int k0) {
        #pragma unroll
        for (int p = 0; p < 2; ++p) {               // A: 1024 chunks
            int f = p * 512 + t;
            int row = f >> 2, c = f & 3;
            int gc = c ^ ((row >> 1) & 3);          // pre-swizzled source chunk
            gload_lds16(Arow0 + (size_t)row * DM + k0 + gc * 8, &As[d][row][c * 8]);
        }
        {                                           // B: 512 chunks
            int row = t >> 2, c = t & 3;
            int gc = c ^ ((row >> 1) & 3);
            gload_lds16(Brow0 + (size_t)row * DM + k0 + gc * 8, &Bs[d][row][c * 8]);
        }
    };
    auto compute = [&](int d) {
        bf16x8 af[4], bfr[4];
        #pragma unroll
        for (int m = 0; m < 4; ++m)
            af[m] = *(const bf16x8*)&As[d][wr + m * 16 + l15][slg * 8];
        #pragma unroll
        for (int n = 0; n < 4; ++n)
            bfr[n] = *(const bf16x8*)&Bs[d][wc + n * 16 + l15][slg * 8];
        #pragma unroll
        for (int m = 0; m < 4; ++m)
            #pragma unroll
            for (int n = 0; n < 4; ++n)
                acc[m][n] = __builtin_amdgcn_mfma_f32_16x16x32_bf16(af[m], bfr[n], acc[m][n], 0, 0, 0);
    };

    stage(0, 0);
    __syncthreads();                                // compiler drains vmcnt(0) here
    for (int kt = 0; kt < NSTEP; kt += 2) {         // literal buffer indices (rule #20)
        if (kt + 1 < NSTEP) stage(1, (kt + 1) * 32);   // prefetch overlaps compute
        compute(0);
        __syncthreads();
        if (kt + 2 < NSTEP) stage(0, (kt + 2) * 32);
        compute(1);
        __syncthreads();
    }

    if (MODE == 1) {
        #pragma unroll
        for (int m = 0; m < 4; ++m) {
            int grow = m0 + wr + m * 16 + lg * 4;
            #pragma unroll
            for (int n = 0; n < 4; ++n) {
                int gcol = n0 + wc + n * 16 + l15;
                float bias = b0[gcol];
                #pragma unroll
                for (int r = 0; r < 4; ++r)
                    Out[(size_t)(grow + r) * DM + gcol] = acc[m][n][r] + bias;
            }
        }
    } else {
        #pragma unroll
        for (int m = 0; m < 4; ++m) {
            int grow = m0 + wr + m * 16 + lg * 4;
            #pragma unroll
            for (int n = 0; n < 4; ++n) {
                int gcol = n0 + wc + n * 16 + l15;
                int which = gcol / DM;
                int c = gcol - which * DM;
                int h = c >> 6, hd = c & 63;
                const float* bp = (which == 0) ? b0 : (which == 1) ? b1 : b2;
                float bias = bp[c];
                #pragma unroll
                for (int r = 0; r < 4; ++r) {
                    int M = grow + r;
                    int bb = M >> 11, ss = M & 2047;
                    float v = acc[m][n][r] + bias;
                    if (which == 0)
                        Qo[(((size_t)bb * NH + h) * SEQ + ss) * HD + hd] = f2bf(v * 0.125f);
                    else if (which == 1)
                        Ko[(((size_t)bb * NH + h) * SEQ + ss) * HD + hd] = f2bf(v);
                    else
                        Vto[(((size_t)bb * NH + h) * HD + hd) * SEQ + ss] = f2bf(v);
                }
            }
        }
    }
}

// ---------------- causal flash attention v2 (unchanged from round 3) ----------------
__global__ __launch_bounds__(512, 4)
void attn_fwd(const u16* __restrict__ Q, const u16* __restrict__ K_,
              const u16* __restrict__ Vt, u16* __restrict__ ctx)
{
    __shared__ u16 Ks[2][64][72];
    __shared__ u16 Vs[2][64][72];

    const int t = threadIdx.x, w = t >> 6, l = t & 63;
    const int l15 = l & 15, lg = l >> 4;
    const int bx = blockIdx.x;
    const int ord = bx / 48;            // ascending => qblk descending (LPT dispatch)
    const int bh  = bx - ord * 48;
    const int qblk = 15 - ord;
    const int b = bh / NH, h = bh - b * NH;
    const int wrow0 = qblk * 128 + w * 16;
    const int jmax = 2 * qblk + 1;

    const u16* Qp = Q + ((size_t)bh * SEQ + wrow0 + l15) * HD;
    bf16x8 qf0 = *(const bf16x8*)(Qp + lg * 8);
    bf16x8 qf1 = *(const bf16x8*)(Qp + 32 + lg * 8);

    f32x4 zf = {0.f, 0.f, 0.f, 0.f};
    f32x4 acc[4];
    #pragma unroll
    for (int d = 0; d < 4; ++d) acc[d] = zf;
    float mi = -INFINITY, li = 0.f;

    const u16* Kbh = K_ + (size_t)bh * SEQ * HD;
    const u16* Vbh = Vt + (size_t)bh * HD * SEQ;
    const int row = t >> 3, c8 = (t & 7) * 8;

    {
        int4 kr = *(const int4*)(Kbh + (size_t)row * HD + c8);
        int4 vr = *(const int4*)(Vbh + (size_t)row * SEQ + c8);
        *(int4*)&Ks[0][row][c8] = kr;
        *(int4*)&Vs[0][row][c8] = vr;
    }
    __syncthreads();

    for (int jt = 0; jt <= jmax; ++jt) {
        const int cur = jt & 1;
        const int j0 = jt << 6;
        int4 kn, vn;
        if (jt < jmax) {
            int j1 = j0 + 64;
            kn = *(const int4*)(Kbh + (size_t)(j1 + row) * HD + c8);
            vn = *(const int4*)(Vbh + (size_t)row * SEQ + j1 + c8);
        }
        if (j0 <= wrow0 + 15) {
            const u16 (*Kc)[72] = Ks[cur];
            const u16 (*Vc)[72] = Vs[cur];
            f32x4 sc[4];
            #pragma unroll
            for (int nt = 0; nt < 4; ++nt) {
                bf16x8 kf0 = *(const bf16x8*)&Kc[nt * 16 + l15][lg * 8];
                bf16x8 kf1 = *(const bf16x8*)&Kc[nt * 16 + l15][32 + lg * 8];
                f32x4 a = zf;
                a = __builtin_amdgcn_mfma_f32_16x16x32_bf16(kf0, qf0, a, 0, 0, 0);
                a = __builtin_amdgcn_mfma_f32_16x16x32_bf16(kf1, qf1, a, 0, 0, 0);
                sc[nt] = a;
            }
            if (j0 + 63 > wrow0) {
                #pragma unroll
                for (int nt = 0; nt < 4; ++nt) {
                    int kb = j0 + nt * 16 + lg * 4;
                    #pragma unroll
                    for (int r = 0; r < 4; ++r)
                        if (kb + r > wrow0 + l15) sc[nt][r] = -INFINITY;
                }
            }
            float cm = sc[0][0];
            #pragma unroll
            for (int nt = 0; nt < 4; ++nt)
                #pragma unroll
                for (int r = 0; r < 4; ++r) cm = fmaxf(cm, sc[nt][r]);
            cm = fmaxf(cm, __shfl_xor(cm, 16));
            cm = fmaxf(cm, __shfl_xor(cm, 32));
            float mn = fmaxf(mi, cm);
            float so = __expf(mi - mn);
            mi = mn;
            float rs = 0.f;
            u32 dw0, dw1, dw2, dw3, dw4, dw5, dw6, dw7;
            {
                float p0, p1, p2, p3;
                p0 = __expf(sc[0][0] - mn); p1 = __expf(sc[0][1] - mn);
                p2 = __expf(sc[0][2] - mn); p3 = __expf(sc[0][3] - mn);
                rs += (p0 + p1) + (p2 + p3); dw0 = pkbf(p0, p1); dw1 = pkbf(p2, p3);
                p0 = __expf(sc[1][0] - mn); p1 = __expf(sc[1][1] - mn);
                p2 = __expf(sc[1][2] - mn); p3 = __expf(sc[1][3] - mn);
                rs += (p0 + p1) + (p2 + p3); dw2 = pkbf(p0, p1); dw3 = pkbf(p2, p3);
                p0 = __expf(sc[2][0] - mn); p1 = __expf(sc[2][1] - mn);
                p2 = __expf(sc[2][2] - mn); p3 = __expf(sc[2][3] - mn);
                rs += (p0 + p1) + (p2 + p3); dw4 = pkbf(p0, p1); dw5 = pkbf(p2, p3);
                p0 = __expf(sc[3][0] - mn); p1 = __expf(sc[3][1] - mn);
                p2 = __expf(sc[3][2] - mn); p3 = __expf(sc[3][3] - mn);
                rs += (p0 + p1) + (p2 + p3); dw6 = pkbf(p0, p1); dw7 = pkbf(p2, p3);
            }
            rs += __shfl_xor(rs, 16);
            rs += __shfl_xor(rs, 32);
            li = li * so + rs;
            float so0 = __shfl(so, lg * 4 + 0), so1 = __shfl(so, lg * 4 + 1);
            float so2 = __shfl(so, lg * 4 + 2), so3 = __shfl(so, lg * 4 + 3);
            #pragma unroll
            for (int d = 0; d < 4; ++d) {
                acc[d][0] *= so0; acc[d][1] *= so1;
                acc[d][2] *= so2; acc[d][3] *= so3;
            }
            bf16x8 pa0 = __builtin_bit_cast(bf16x8, make_int4((int)dw0, (int)dw1, (int)dw2, (int)dw3));
            bf16x8 pa1 = __builtin_bit_cast(bf16x8, make_int4((int)dw4, (int)dw5, (int)dw6, (int)dw7));
            #pragma unroll
            for (int d = 0; d < 4; ++d) {
                const u16* vrow = Vc[d * 16 + l15];
                int2 a0 = *(const int2*)(vrow + lg * 4);
                int2 a1 = *(const int2*)(vrow + 16 + lg * 4);
                int2 a2 = *(const int2*)(vrow + 32 + lg * 4);
                int2 a3 = *(const int2*)(vrow + 48 + lg * 4);
                bf16x8 vf0 = __builtin_bit_cast(bf16x8, make_int4(a0.x, a0.y, a1.x, a1.y));
                bf16x8 vf1 = __builtin_bit_cast(bf16x8, make_int4(a2.x, a2.y, a3.x, a3.y));
                acc[d] = __builtin_amdgcn_mfma_f32_16x16x32_bf16(pa0, vf0, acc[d], 0, 0, 0);
                acc[d] = __builtin_amdgcn_mfma_f32_16x16x32_bf16(pa1, vf1, acc[d], 0, 0, 0);
            }
        }
        if (jt < jmax) {
            *(int4*)&Ks[cur ^ 1][row][c8] = kn;
            *(int4*)&Vs[cur ^ 1][row][c8] = vn;
        }
        __syncthreads();
    }

    float il0 = 1.0f / __shfl(li, lg * 4 + 0);
    float il1 = 1.0f / __shfl(li, lg * 4 + 1);
    float il2 = 1.0f / __shfl(li, lg * 4 + 2);
    float il3 = 1.0f / __shfl(li, lg * 4 + 3);
    #pragma unroll
    for (int r = 0; r < 4; ++r) {
        float il = (r == 0) ? il0 : (r == 1) ? il1 : (r == 2) ? il2 : il3;
        int s = wrow0 + lg * 4 + r;
        size_t base = ((size_t)b * SEQ + s) * DM + h * HD;
        #pragma unroll
        for (int d = 0; d < 4; ++d)
            ctx[base + d * 16 + l15] = f2bf(acc[d][r] * il);
    }
}

extern "C" void kernel_launch(void* const* d_in, const int* in_sizes, int n_in,
                              void* d_out, int out_size, void* d_ws, size_t ws_size,
                              hipStream_t stream) {
    const float* x  = (const float*)d_in[0];
    const float* Wq = (const float*)d_in[1];
    const float* bq = (const float*)d_in[2];
    const float* Wk = (const float*)d_in[3];
    const float* bk = (const float*)d_in[4];
    const float* Wv = (const float*)d_in[5];
    const float* bv = (const float*)d_in[6];
    const float* Wo = (const float*)d_in[7];
    const float* bo = (const float*)d_in[8];
    float* out = (float*)d_out;

    char* ws = (char*)d_ws;
    u16* xb  = (u16*)(ws);                    // 8192*768*2      = 12,582,912
    u16* Wt  = (u16*)(ws + 12582912);         // 2304*768*2      =  3,538,944
    u16* Wto = (u16*)(ws + 16121856);         // 768*768*2       =  1,179,648
    u16* Qw  = (u16*)(ws + 17301504);         // [BH][S][64]     = 12,582,912
    u16* Kw  = (u16*)(ws + 29884416);         // [BH][S][64]     = 12,582,912
    u16* Vtw = (u16*)(ws + 42467328);         // [BH][64][S]     = 12,582,912
    u16* ctx = (u16*)(ws + 55050240);         // [B][S][768]     = 12,582,912

    cvt_x<<<6144, 256, 0, stream>>>(x, xb, NTOK * DM / 4);
    dim3 tb(32, 8), tg4(24, 24, 4);
    transpose_w4<<<tg4, tb, 0, stream>>>(Wq, Wk, Wv, Wo, Wt, Wto);

    dim3 g2(32, 18);
    gemm256<0><<<g2, 512, 0, stream>>>(xb, Wt, bq, bk, bv, Qw, Kw, Vtw, nullptr);
    attn_fwd<<<768, 512, 0, stream>>>(Qw, Kw, Vtw, ctx);
    dim3 g4(32, 6);
    gemm256<1><<<g4, 512, 0, stream>>>(ctx, Wto, bo, nullptr, nullptr, nullptr, nullptr, nullptr, out);
}

// Round 5
// 164.763 us; speedup vs baseline: 1.6453x; 1.0037x over previous
//
#include <hip/hip_runtime.h>
#include <stdint.h>

#define DM    768
#define NH    12
#define HD    64
#define BATCH 4
#define SEQ   2048
#define NTOK  (BATCH*SEQ)   // 8192
#define NKT   12            // 768 / 64 K-tiles

typedef unsigned int   u32;
typedef unsigned short u16;
using bf16x8 = __attribute__((ext_vector_type(8))) short;
using f32x4  = __attribute__((ext_vector_type(4))) float;

__device__ __forceinline__ u16 f2bf(float f) {
    u32 u = __float_as_uint(f);
    u = (u + 0x7FFFu + ((u >> 16) & 1u)) >> 16;
    return (u16)u;
}

__device__ __forceinline__ u32 pkbf(float a, float b) {
    u32 r;
    asm("v_cvt_pk_bf16_f32 %0, %1, %2" : "=v"(r) : "v"(a), "v"(b));
    return r;
}

__device__ __forceinline__ void gload_lds16(const void* gptr, void* ldsptr) {
    __builtin_amdgcn_global_load_lds(
        (__attribute__((address_space(1))) const u32*)gptr,
        (__attribute__((address_space(3))) u32*)ldsptr, 16, 0, 0);
}

// ---------------- x fp32 -> bf16 (vectorized) ----------------
__global__ void cvt_x(const float* __restrict__ x, u16* __restrict__ xb, int n4) {
    int i = blockIdx.x * blockDim.x + threadIdx.x;
    if (i >= n4) return;
    float4 v = ((const float4*)x)[i];
    ushort4 o;
    o.x = f2bf(v.x); o.y = f2bf(v.y); o.z = f2bf(v.z); o.w = f2bf(v.w);
    ((ushort4*)xb)[i] = o;
}

// ------- all 4 weight transposes in ONE launch: W [k][n] fp32 -> Wt [n][k] bf16 -------
__global__ void transpose_w4(const float* __restrict__ q, const float* __restrict__ k,
                             const float* __restrict__ v, const float* __restrict__ o,
                             u16* __restrict__ Wt, u16* __restrict__ Wto) {
    __shared__ float tile[32][33];
    int z = blockIdx.z;
    const float* W = (z == 0) ? q : (z == 1) ? k : (z == 2) ? v : o;
    u16* D = (z < 3) ? (Wt + (size_t)z * DM * DM) : Wto;
    int tx = threadIdx.x, ty = threadIdx.y;   // 32 x 8
    int x0 = blockIdx.x * 32, y0 = blockIdx.y * 32;
    #pragma unroll
    for (int i = 0; i < 32; i += 8)
        tile[ty + i][tx] = W[(size_t)(y0 + ty + i) * DM + x0 + tx];
    __syncthreads();
    #pragma unroll
    for (int i = 0; i < 32; i += 8)
        D[(size_t)(x0 + ty + i) * DM + y0 + tx] = f2bf(tile[tx][ty + i]);
}

// ---------- bf16 MFMA GEMM, BK=64, raw-barrier pipeline with counted vmcnt ----------
// 8 waves (512 thr) as 2M x 4N. BN=192 (wave-N = 48, 3 frags).
// MODE 0: BM=256 (wave-M = 128, 8 frags). A=xb[8192][768], Bt=Wqkv^T[2304][768]
//         -> Q(scaled)/K [BH][S][64], V^T [BH][64][S]
// MODE 1: BM=128 (wave-M = 64, 4 frags).  A=ctx[8192][768], Bt=Wo^T[768][768]
//         -> Out fp32 [8192][768] + bias
// LDS XOR swizzle: LDS chunk c of row r holds global chunk c ^ (r&7); readers
// fetch chunk (kk*4+lg) ^ (l15&7)  (both-sides involution, rule #21).
// Loads for tile t+1 issue at iter-t start; single s_waitcnt vmcnt(0) at iter
// end (loads span the full K-tile compute) + raw s_barrier (no implicit drain).
template <int MODE>
__global__ __launch_bounds__(512, 2)
void gemm_pipe(const u16* __restrict__ A, const u16* __restrict__ Bt,
               const float* __restrict__ b0, const float* __restrict__ b1,
               const float* __restrict__ b2,
               u16* __restrict__ Qo, u16* __restrict__ Ko, u16* __restrict__ Vto,
               float* __restrict__ Out)
{
    constexpr int BM = (MODE == 0) ? 256 : 128;
    constexpr int MF = BM / 32;                 // per-wave M frags (8 / 4)
    constexpr int ALOADS = BM * 8 / 512;        // per-thread A chunks (4 / 2)

    __shared__ u16 As[2][BM][64];
    __shared__ u16 Bs[2][192][64];

    const int t = threadIdx.x;
    const int w = t >> 6, l = t & 63;
    const int l15 = l & 15, lg = l >> 4;
    const int m0 = blockIdx.x * BM;
    const int n0 = blockIdx.y * 192;
    const int waveM = (w >> 2) * (BM / 2);
    const int waveN = (w & 3) * 48;

    f32x4 zf = {0.f, 0.f, 0.f, 0.f};
    f32x4 acc[MF][3];
    #pragma unroll
    for (int i = 0; i < MF; ++i)
        #pragma unroll
        for (int j = 0; j < 3; ++j) acc[i][j] = zf;

    const u16* Arow0 = A  + (size_t)m0 * DM;
    const u16* Brow0 = Bt + (size_t)n0 * DM;

    auto stage = [&](int d, int k0) {
        #pragma unroll
        for (int i = 0; i < ALOADS; ++i) {
            int f = i * 512 + t;
            int row = f >> 3, c = f & 7;
            int gc = c ^ (row & 7);
            gload_lds16(Arow0 + (size_t)row * DM + k0 + gc * 8, &As[d][row][c * 8]);
        }
        #pragma unroll
        for (int i = 0; i < 3; ++i) {           // 192*8/512 = 3
            int f = i * 512 + t;
            int row = f >> 3, c = f & 7;
            int gc = c ^ (row & 7);
            gload_lds16(Brow0 + (size_t)row * DM + k0 + gc * 8, &Bs[d][row][c * 8]);
        }
    };
    auto phase = [&](int d, int kk) {
        const int ch = ((kk * 4 + lg) ^ (l15 & 7)) * 8;
        bf16x8 af[MF], bfr[3];
        #pragma unroll
        for (int m = 0; m < MF; ++m)
            af[m] = *(const bf16x8*)&As[d][waveM + m * 16 + l15][ch];
        #pragma unroll
        for (int n = 0; n < 3; ++n)
            bfr[n] = *(const bf16x8*)&Bs[d][waveN + n * 16 + l15][ch];
        __builtin_amdgcn_s_setprio(1);
        #pragma unroll
        for (int m = 0; m < MF; ++m)
            #pragma unroll
            for (int n = 0; n < 3; ++n)
                acc[m][n] = __builtin_amdgcn_mfma_f32_16x16x32_bf16(af[m], bfr[n], acc[m][n], 0, 0, 0);
        __builtin_amdgcn_s_setprio(0);
    };

    stage(0, 0);
    asm volatile("s_waitcnt vmcnt(0)" ::: "memory");
    __builtin_amdgcn_s_barrier();
    __builtin_amdgcn_sched_barrier(0);

    for (int tt = 0; tt < NKT; ++tt) {
        const int c = tt & 1;
        if (tt < NKT - 1) stage(c ^ 1, (tt + 1) * 64);   // issue-early, gated at iter end
        phase(c, 0);
        __builtin_amdgcn_s_barrier();                    // raw: no vmcnt drain
        __builtin_amdgcn_sched_barrier(0);
        phase(c, 1);
        if (tt < NKT - 1) asm volatile("s_waitcnt vmcnt(0)" ::: "memory");
        __builtin_amdgcn_s_barrier();
        __builtin_amdgcn_sched_barrier(0);
    }

    if (MODE == 1) {
        #pragma unroll
        for (int m = 0; m < MF; ++m) {
            int grow = m0 + waveM + m * 16 + lg * 4;
            #pragma unroll
            for (int n = 0; n < 3; ++n) {
                int gcol = n0 + waveN + n * 16 + l15;
                float bias = b0[gcol];
                #pragma unroll
                for (int r = 0; r < 4; ++r)
                    Out[(size_t)(grow + r) * DM + gcol] = acc[m][n][r] + bias;
            }
        }
    } else {
        #pragma unroll
        for (int m = 0; m < MF; ++m) {
            int grow = m0 + waveM + m * 16 + lg * 4;
            #pragma unroll
            for (int n = 0; n < 3; ++n) {
                int gcol = n0 + waveN + n * 16 + l15;
                int which = gcol / DM;
                int cc = gcol - which * DM;
                int h = cc >> 6, hd = cc & 63;
                const float* bp = (which == 0) ? b0 : (which == 1) ? b1 : b2;
                float bias = bp[cc];
                #pragma unroll
                for (int r = 0; r < 4; ++r) {
                    int M = grow + r;
                    int bb = M >> 11, ss = M & 2047;
                    float v = acc[m][n][r] + bias;
                    if (which == 0)
                        Qo[(((size_t)bb * NH + h) * SEQ + ss) * HD + hd] = f2bf(v * 0.125f);
                    else if (which == 1)
                        Ko[(((size_t)bb * NH + h) * SEQ + ss) * HD + hd] = f2bf(v);
                    else
                        Vto[(((size_t)bb * NH + h) * HD + hd) * SEQ + ss] = f2bf(v);
                }
            }
        }
    }
}

// ---------------- causal flash attention v2 (unchanged) ----------------
__global__ __launch_bounds__(512, 4)
void attn_fwd(const u16* __restrict__ Q, const u16* __restrict__ K_,
              const u16* __restrict__ Vt, u16* __restrict__ ctx)
{
    __shared__ u16 Ks[2][64][72];
    __shared__ u16 Vs[2][64][72];

    const int t = threadIdx.x, w = t >> 6, l = t & 63;
    const int l15 = l & 15, lg = l >> 4;
    const int bx = blockIdx.x;
    const int ord = bx / 48;            // ascending => qblk descending (LPT dispatch)
    const int bh  = bx - ord * 48;
    const int qblk = 15 - ord;
    const int b = bh / NH, h = bh - b * NH;
    const int wrow0 = qblk * 128 + w * 16;
    const int jmax = 2 * qblk + 1;

    const u16* Qp = Q + ((size_t)bh * SEQ + wrow0 + l15) * HD;
    bf16x8 qf0 = *(const bf16x8*)(Qp + lg * 8);
    bf16x8 qf1 = *(const bf16x8*)(Qp + 32 + lg * 8);

    f32x4 zf = {0.f, 0.f, 0.f, 0.f};
    f32x4 acc[4];
    #pragma unroll
    for (int d = 0; d < 4; ++d) acc[d] = zf;
    float mi = -INFINITY, li = 0.f;

    const u16* Kbh = K_ + (size_t)bh * SEQ * HD;
    const u16* Vbh = Vt + (size_t)bh * HD * SEQ;
    const int row = t >> 3, c8 = (t & 7) * 8;

    {
        int4 kr = *(const int4*)(Kbh + (size_t)row * HD + c8);
        int4 vr = *(const int4*)(Vbh + (size_t)row * SEQ + c8);
        *(int4*)&Ks[0][row][c8] = kr;
        *(int4*)&Vs[0][row][c8] = vr;
    }
    __syncthreads();

    for (int jt = 0; jt <= jmax; ++jt) {
        const int cur = jt & 1;
        const int j0 = jt << 6;
        int4 kn, vn;
        if (jt < jmax) {
            int j1 = j0 + 64;
            kn = *(const int4*)(Kbh + (size_t)(j1 + row) * HD + c8);
            vn = *(const int4*)(Vbh + (size_t)row * SEQ + j1 + c8);
        }
        if (j0 <= wrow0 + 15) {
            const u16 (*Kc)[72] = Ks[cur];
            const u16 (*Vc)[72] = Vs[cur];
            f32x4 sc[4];
            #pragma unroll
            for (int nt = 0; nt < 4; ++nt) {
                bf16x8 kf0 = *(const bf16x8*)&Kc[nt * 16 + l15][lg * 8];
                bf16x8 kf1 = *(const bf16x8*)&Kc[nt * 16 + l15][32 + lg * 8];
                f32x4 a = zf;
                a = __builtin_amdgcn_mfma_f32_16x16x32_bf16(kf0, qf0, a, 0, 0, 0);
                a = __builtin_amdgcn_mfma_f32_16x16x32_bf16(kf1, qf1, a, 0, 0, 0);
                sc[nt] = a;
            }
            if (j0 + 63 > wrow0) {
                #pragma unroll
                for (int nt = 0; nt < 4; ++nt) {
                    int kb = j0 + nt * 16 + lg * 4;
                    #pragma unroll
                    for (int r = 0; r < 4; ++r)
                        if (kb + r > wrow0 + l15) sc[nt][r] = -INFINITY;
                }
            }
            float cm = sc[0][0];
            #pragma unroll
            for (int nt = 0; nt < 4; ++nt)
                #pragma unroll
                for (int r = 0; r < 4; ++r) cm = fmaxf(cm, sc[nt][r]);
            cm = fmaxf(cm, __shfl_xor(cm, 16));
            cm = fmaxf(cm, __shfl_xor(cm, 32));
            float mn = fmaxf(mi, cm);
            float so = __expf(mi - mn);
            mi = mn;
            float rs = 0.f;
            u32 dw0, dw1, dw2, dw3, dw4, dw5, dw6, dw7;
            {
                float p0, p1, p2, p3;
                p0 = __expf(sc[0][0] - mn); p1 = __expf(sc[0][1] - mn);
                p2 = __expf(sc[0][2] - mn); p3 = __expf(sc[0][3] - mn);
                rs += (p0 + p1) + (p2 + p3); dw0 = pkbf(p0, p1); dw1 = pkbf(p2, p3);
                p0 = __expf(sc[1][0] - mn); p1 = __expf(sc[1][1] - mn);
                p2 = __expf(sc[1][2] - mn); p3 = __expf(sc[1][3] - mn);
                rs += (p0 + p1) + (p2 + p3); dw2 = pkbf(p0, p1); dw3 = pkbf(p2, p3);
                p0 = __expf(sc[2][0] - mn); p1 = __expf(sc[2][1] - mn);
                p2 = __expf(sc[2][2] - mn); p3 = __expf(sc[2][3] - mn);
                rs += (p0 + p1) + (p2 + p3); dw4 = pkbf(p0, p1); dw5 = pkbf(p2, p3);
                p0 = __expf(sc[3][0] - mn); p1 = __expf(sc[3][1] - mn);
                p2 = __expf(sc[3][2] - mn); p3 = __expf(sc[3][3] - mn);
                rs += (p0 + p1) + (p2 + p3); dw6 = pkbf(p0, p1); dw7 = pkbf(p2, p3);
            }
            rs += __shfl_xor(rs, 16);
            rs += __shfl_xor(rs, 32);
            li = li * so + rs;
            float so0 = __shfl(so, lg * 4 + 0), so1 = __shfl(so, lg * 4 + 1);
            float so2 = __shfl(so, lg * 4 + 2), so3 = __shfl(so, lg * 4 + 3);
            #pragma unroll
            for (int d = 0; d < 4; ++d) {
                acc[d][0] *= so0; acc[d][1] *= so1;
                acc[d][2] *= so2; acc[d][3] *= so3;
            }
            bf16x8 pa0 = __builtin_bit_cast(bf16x8, make_int4((int)dw0, (int)dw1, (int)dw2, (int)dw3));
            bf16x8 pa1 = __builtin_bit_cast(bf16x8, make_int4((int)dw4, (int)dw5, (int)dw6, (int)dw7));
            #pragma unroll
            for (int d = 0; d < 4; ++d) {
                const u16* vrow = Vc[d * 16 + l15];
                int2 a0 = *(const int2*)(vrow + lg * 4);
                int2 a1 = *(const int2*)(vrow + 16 + lg * 4);
                int2 a2 = *(const int2*)(vrow + 32 + lg * 4);
                int2 a3 = *(const int2*)(vrow + 48 + lg * 4);
                bf16x8 vf0 = __builtin_bit_cast(bf16x8, make_int4(a0.x, a0.y, a1.x, a1.y));
                bf16x8 vf1 = __builtin_bit_cast(bf16x8, make_int4(a2.x, a2.y, a3.x, a3.y));
                acc[d] = __builtin_amdgcn_mfma_f32_16x16x32_bf16(pa0, vf0, acc[d], 0, 0, 0);
                acc[d] = __builtin_amdgcn_mfma_f32_16x16x32_bf16(pa1, vf1, acc[d], 0, 0, 0);
            }
        }
        if (jt < jmax) {
            *(int4*)&Ks[cur ^ 1][row][c8] = kn;
            *(int4*)&Vs[cur ^ 1][row][c8] = vn;
        }
        __syncthreads();
    }

    float il0 = 1.0f / __shfl(li, lg * 4 + 0);
    float il1 = 1.0f / __shfl(li, lg * 4 + 1);
    float il2 = 1.0f / __shfl(li, lg * 4 + 2);
    float il3 = 1.0f / __shfl(li, lg * 4 + 3);
    #pragma unroll
    for (int r = 0; r < 4; ++r) {
        float il = (r == 0) ? il0 : (r == 1) ? il1 : (r == 2) ? il2 : il3;
        int s = wrow0 + lg * 4 + r;
        size_t base = ((size_t)b * SEQ + s) * DM + h * HD;
        #pragma unroll
        for (int d = 0; d < 4; ++d)
            ctx[base + d * 16 + l15] = f2bf(acc[d][r] * il);
    }
}

extern "C" void kernel_launch(void* const* d_in, const int* in_sizes, int n_in,
                              void* d_out, int out_size, void* d_ws, size_t ws_size,
                              hipStream_t stream) {
    const float* x  = (const float*)d_in[0];
    const float* Wq = (const float*)d_in[1];
    const float* bq = (const float*)d_in[2];
    const float* Wk = (const float*)d_in[3];
    const float* bk = (const float*)d_in[4];
    const float* Wv = (const float*)d_in[5];
    const float* bv = (const float*)d_in[6];
    const float* Wo = (const float*)d_in[7];
    const float* bo = (const float*)d_in[8];
    float* out = (float*)d_out;

    char* ws = (char*)d_ws;
    u16* xb  = (u16*)(ws);                    // 8192*768*2      = 12,582,912
    u16* Wt  = (u16*)(ws + 12582912);         // 2304*768*2      =  3,538,944
    u16* Wto = (u16*)(ws + 16121856);         // 768*768*2       =  1,179,648
    u16* Qw  = (u16*)(ws + 17301504);         // [BH][S][64]     = 12,582,912
    u16* Kw  = (u16*)(ws + 29884416);         // [BH][S][64]     = 12,582,912
    u16* Vtw = (u16*)(ws + 42467328);         // [BH][64][S]     = 12,582,912
    u16* ctx = (u16*)(ws + 55050240);         // [B][S][768]     = 12,582,912

    cvt_x<<<6144, 256, 0, stream>>>(x, xb, NTOK * DM / 4);
    dim3 tb(32, 8), tg4(24, 24, 4);
    transpose_w4<<<tg4, tb, 0, stream>>>(Wq, Wk, Wv, Wo, Wt, Wto);

    dim3 g2(32, 12);
    gemm_pipe<0><<<g2, 512, 0, stream>>>(xb, Wt, bq, bk, bv, Qw, Kw, Vtw, nullptr);
    attn_fwd<<<768, 512, 0, stream>>>(Qw, Kw, Vtw, ctx);
    dim3 g4(64, 4);
    gemm_pipe<1><<<g4, 512, 0, stream>>>(ctx, Wto, bo, nullptr, nullptr, nullptr, nullptr, nullptr, out);
}

// Round 6
// 160.236 us; speedup vs baseline: 1.6918x; 1.0283x over previous
//
#include <hip/hip_runtime.h>
#include <stdint.h>

#define DM    768
#define NH    12
#define HD    64
#define BATCH 4
#define SEQ   2048
#define NTOK  (BATCH*SEQ)   // 8192
#define NKT   12            // 768 / 64 K-tiles

typedef unsigned int   u32;
typedef unsigned short u16;
using bf16x8 = __attribute__((ext_vector_type(8))) short;
using f32x4  = __attribute__((ext_vector_type(4))) float;

__device__ __forceinline__ u16 f2bf(float f) {
    u32 u = __float_as_uint(f);
    u = (u + 0x7FFFu + ((u >> 16) & 1u)) >> 16;
    return (u16)u;
}

__device__ __forceinline__ u32 pkbf(float a, float b) {
    u32 r;
    asm("v_cvt_pk_bf16_f32 %0, %1, %2" : "=v"(r) : "v"(a), "v"(b));
    return r;
}

template <int N>
__device__ __forceinline__ void waitvm() {
    if constexpr (N == 0)      asm volatile("s_waitcnt vmcnt(0)" ::: "memory");
    else if constexpr (N == 5) asm volatile("s_waitcnt vmcnt(5)" ::: "memory");
    else if constexpr (N == 8) asm volatile("s_waitcnt vmcnt(8)" ::: "memory");
    else                       static_assert(N == 0 || N == 5 || N == 8, "add literal");
}

__device__ __forceinline__ void gload_lds16(const void* gptr, void* ldsptr) {
    __builtin_amdgcn_global_load_lds(
        (__attribute__((address_space(1))) const u32*)gptr,
        (__attribute__((address_space(3))) u32*)ldsptr, 16, 0, 0);
}

// ---------------- x fp32 -> bf16 (vectorized) ----------------
__global__ void cvt_x(const float* __restrict__ x, u16* __restrict__ xb, int n4) {
    int i = blockIdx.x * blockDim.x + threadIdx.x;
    if (i >= n4) return;
    float4 v = ((const float4*)x)[i];
    ushort4 o;
    o.x = f2bf(v.x); o.y = f2bf(v.y); o.z = f2bf(v.z); o.w = f2bf(v.w);
    ((ushort4*)xb)[i] = o;
}

// ------- all 4 weight transposes in ONE launch: W [k][n] fp32 -> Wt [n][k] bf16 -------
__global__ void transpose_w4(const float* __restrict__ q, const float* __restrict__ k,
                             const float* __restrict__ v, const float* __restrict__ o,
                             u16* __restrict__ Wt, u16* __restrict__ Wto) {
    __shared__ float tile[32][33];
    int z = blockIdx.z;
    const float* W = (z == 0) ? q : (z == 1) ? k : (z == 2) ? v : o;
    u16* D = (z < 3) ? (Wt + (size_t)z * DM * DM) : Wto;
    int tx = threadIdx.x, ty = threadIdx.y;   // 32 x 8
    int x0 = blockIdx.x * 32, y0 = blockIdx.y * 32;
    #pragma unroll
    for (int i = 0; i < 32; i += 8)
        tile[ty + i][tx] = W[(size_t)(y0 + ty + i) * DM + x0 + tx];
    __syncthreads();
    #pragma unroll
    for (int i = 0; i < 32; i += 8)
        D[(size_t)(x0 + ty + i) * DM + y0 + tx] = f2bf(tile[tx][ty + i]);
}

// ---- bf16 MFMA GEMM, BK=64, 2-tiles-ahead pipeline with counted vmcnt (T3/T4) ----
// 8 waves (512 thr) as 2M x 4N.
// MODE 0: BM=256, BN=256. A=xb[8192][768], Bt=Wqkv^T[2304][768]
//         -> Q(scaled)/K [BH][S][64], V^T [BH][64][S].  Grid 32x9.
// MODE 1: BM=128, BN=192. A=ctx[8192][768], Bt=Wo^T[768][768]
//         -> Out fp32 [8192][768] + bias.               Grid 64x4.
// LDS XOR swizzle: LDS chunk c of row r holds global chunk c ^ (r&7); readers
// fetch chunk (kk*4+lg) ^ (l15&7)  (both-sides involution, rule #21).
// Pipeline: tiles t and t+1 always in flight; iter t waits vmcnt(TL) (tile t
// done, t+1 still flying), computes both phases (no mid-barrier), then stages
// tile t+2 into the freed buffer. vmcnt(0) only on the final tile.
template <int MODE>
__global__ __launch_bounds__(512, 2)
void gemm_pipe(const u16* __restrict__ A, const u16* __restrict__ Bt,
               const float* __restrict__ b0, const float* __restrict__ b1,
               const float* __restrict__ b2,
               u16* __restrict__ Qo, u16* __restrict__ Ko, u16* __restrict__ Vto,
               float* __restrict__ Out)
{
    constexpr int BM = (MODE == 0) ? 256 : 128;
    constexpr int BN = (MODE == 0) ? 256 : 192;
    constexpr int MF = BM / 32;                 // per-wave M frags (8 / 4)
    constexpr int NF = BN / 64;                 // per-wave N frags (4 / 3)
    constexpr int AL = BM / 64;                 // per-thread A chunks (4 / 2)
    constexpr int BL = BN / 64;                 // per-thread B chunks (4 / 3)
    constexpr int TL = AL + BL;                 // loads per stage (8 / 5)

    __shared__ u16 As[2][BM][64];
    __shared__ u16 Bs[2][BN][64];

    const int t = threadIdx.x;
    const int w = t >> 6, l = t & 63;
    const int l15 = l & 15, lg = l >> 4;
    const int m0 = blockIdx.x * BM;
    const int n0 = blockIdx.y * BN;
    const int waveM = (w >> 2) * (BM / 2);
    const int waveN = (w & 3) * (BN / 4);

    f32x4 zf = {0.f, 0.f, 0.f, 0.f};
    f32x4 acc[MF][NF];
    #pragma unroll
    for (int i = 0; i < MF; ++i)
        #pragma unroll
        for (int j = 0; j < NF; ++j) acc[i][j] = zf;

    const u16* Arow0 = A  + (size_t)m0 * DM;
    const u16* Brow0 = Bt + (size_t)n0 * DM;

    auto stage = [&](int d, int k0) {
        #pragma unroll
        for (int i = 0; i < AL; ++i) {
            int f = i * 512 + t;
            int row = f >> 3, c = f & 7;
            int gc = c ^ (row & 7);
            gload_lds16(Arow0 + (size_t)row * DM + k0 + gc * 8, &As[d][row][c * 8]);
        }
        #pragma unroll
        for (int i = 0; i < BL; ++i) {
            int f = i * 512 + t;
            int row = f >> 3, c = f & 7;
            int gc = c ^ (row & 7);
            gload_lds16(Brow0 + (size_t)row * DM + k0 + gc * 8, &Bs[d][row][c * 8]);
        }
    };
    auto phase = [&](int d, int kk) {
        const int ch = ((kk * 4 + lg) ^ (l15 & 7)) * 8;
        bf16x8 af[MF], bfr[NF];
        #pragma unroll
        for (int m = 0; m < MF; ++m)
            af[m] = *(const bf16x8*)&As[d][waveM + m * 16 + l15][ch];
        #pragma unroll
        for (int n = 0; n < NF; ++n)
            bfr[n] = *(const bf16x8*)&Bs[d][waveN + n * 16 + l15][ch];
        __builtin_amdgcn_s_setprio(1);
        #pragma unroll
        for (int m = 0; m < MF; ++m)
            #pragma unroll
            for (int n = 0; n < NF; ++n)
                acc[m][n] = __builtin_amdgcn_mfma_f32_16x16x32_bf16(af[m], bfr[n], acc[m][n], 0, 0, 0);
        __builtin_amdgcn_s_setprio(0);
    };

    stage(0, 0);
    stage(1, 64);

    for (int tt = 0; tt < NKT - 1; ++tt) {
        const int c = tt & 1;
        waitvm<TL>();                            // own tile-t loads done; t+1 in flight
        __builtin_amdgcn_s_barrier();            // all waves' tile-t loads visible
        __builtin_amdgcn_sched_barrier(0);
        phase(c, 0);
        phase(c, 1);
        __builtin_amdgcn_sched_barrier(0);
        __builtin_amdgcn_s_barrier();            // all waves done reading buf c
        __builtin_amdgcn_sched_barrier(0);
        if (tt + 2 < NKT) stage(c, (tt + 2) * 64);
    }
    {
        waitvm<0>();                             // final tile: drain
        __builtin_amdgcn_s_barrier();
        __builtin_amdgcn_sched_barrier(0);
        phase((NKT - 1) & 1, 0);
        phase((NKT - 1) & 1, 1);
    }

    if (MODE == 1) {
        #pragma unroll
        for (int m = 0; m < MF; ++m) {
            int grow = m0 + waveM + m * 16 + lg * 4;
            #pragma unroll
            for (int n = 0; n < NF; ++n) {
                int gcol = n0 + waveN + n * 16 + l15;
                float bias = b0[gcol];
                #pragma unroll
                for (int r = 0; r < 4; ++r)
                    Out[(size_t)(grow + r) * DM + gcol] = acc[m][n][r] + bias;
            }
        }
    } else {
        const int which = n0 / DM;               // block-uniform (BN=256 divides 768 blocks)
        #pragma unroll
        for (int m = 0; m < MF; ++m) {
            int grow = m0 + waveM + m * 16 + lg * 4;
            int bb = grow >> 11, ss = grow & 2047;
            #pragma unroll
            for (int n = 0; n < NF; ++n) {
                int gcol = n0 + waveN + n * 16 + l15;
                int cc = gcol - which * DM;
                int h = cc >> 6, hd = cc & 63;
                if (which == 0) {
                    float bias = b0[cc];
                    #pragma unroll
                    for (int r = 0; r < 4; ++r)
                        Qo[(((size_t)bb * NH + h) * SEQ + (ss + r)) * HD + hd] =
                            f2bf((acc[m][n][r] + bias) * 0.125f);
                } else if (which == 1) {
                    float bias = b1[cc];
                    #pragma unroll
                    for (int r = 0; r < 4; ++r)
                        Ko[(((size_t)bb * NH + h) * SEQ + (ss + r)) * HD + hd] =
                            f2bf(acc[m][n][r] + bias);
                } else {
                    float bias = b2[cc];
                    u32 lo = pkbf(acc[m][n][0] + bias, acc[m][n][1] + bias);
                    u32 hi = pkbf(acc[m][n][2] + bias, acc[m][n][3] + bias);
                    *(int2*)&Vto[(((size_t)bb * NH + h) * HD + hd) * SEQ + ss] =
                        make_int2((int)lo, (int)hi);
                }
            }
        }
    }
}

// ---------------- causal flash attention v2 (unchanged) ----------------
__global__ __launch_bounds__(512, 4)
void attn_fwd(const u16* __restrict__ Q, const u16* __restrict__ K_,
              const u16* __restrict__ Vt, u16* __restrict__ ctx)
{
    __shared__ u16 Ks[2][64][72];
    __shared__ u16 Vs[2][64][72];

    const int t = threadIdx.x, w = t >> 6, l = t & 63;
    const int l15 = l & 15, lg = l >> 4;
    const int bx = blockIdx.x;
    const int ord = bx / 48;            // ascending => qblk descending (LPT dispatch)
    const int bh  = bx - ord * 48;
    const int qblk = 15 - ord;
    const int b = bh / NH, h = bh - b * NH;
    const int wrow0 = qblk * 128 + w * 16;
    const int jmax = 2 * qblk + 1;

    const u16* Qp = Q + ((size_t)bh * SEQ + wrow0 + l15) * HD;
    bf16x8 qf0 = *(const bf16x8*)(Qp + lg * 8);
    bf16x8 qf1 = *(const bf16x8*)(Qp + 32 + lg * 8);

    f32x4 zf = {0.f, 0.f, 0.f, 0.f};
    f32x4 acc[4];
    #pragma unroll
    for (int d = 0; d < 4; ++d) acc[d] = zf;
    float mi = -INFINITY, li = 0.f;

    const u16* Kbh = K_ + (size_t)bh * SEQ * HD;
    const u16* Vbh = Vt + (size_t)bh * HD * SEQ;
    const int row = t >> 3, c8 = (t & 7) * 8;

    {
        int4 kr = *(const int4*)(Kbh + (size_t)row * HD + c8);
        int4 vr = *(const int4*)(Vbh + (size_t)row * SEQ + c8);
        *(int4*)&Ks[0][row][c8] = kr;
        *(int4*)&Vs[0][row][c8] = vr;
    }
    __syncthreads();

    for (int jt = 0; jt <= jmax; ++jt) {
        const int cur = jt & 1;
        const int j0 = jt << 6;
        int4 kn, vn;
        if (jt < jmax) {
            int j1 = j0 + 64;
            kn = *(const int4*)(Kbh + (size_t)(j1 + row) * HD + c8);
            vn = *(const int4*)(Vbh + (size_t)row * SEQ + j1 + c8);
        }
        if (j0 <= wrow0 + 15) {
            const u16 (*Kc)[72] = Ks[cur];
            const u16 (*Vc)[72] = Vs[cur];
            f32x4 sc[4];
            #pragma unroll
            for (int nt = 0; nt < 4; ++nt) {
                bf16x8 kf0 = *(const bf16x8*)&Kc[nt * 16 + l15][lg * 8];
                bf16x8 kf1 = *(const bf16x8*)&Kc[nt * 16 + l15][32 + lg * 8];
                f32x4 a = zf;
                a = __builtin_amdgcn_mfma_f32_16x16x32_bf16(kf0, qf0, a, 0, 0, 0);
                a = __builtin_amdgcn_mfma_f32_16x16x32_bf16(kf1, qf1, a, 0, 0, 0);
                sc[nt] = a;
            }
            if (j0 + 63 > wrow0) {
                #pragma unroll
                for (int nt = 0; nt < 4; ++nt) {
                    int kb = j0 + nt * 16 + lg * 4;
                    #pragma unroll
                    for (int r = 0; r < 4; ++r)
                        if (kb + r > wrow0 + l15) sc[nt][r] = -INFINITY;
                }
            }
            float cm = sc[0][0];
            #pragma unroll
            for (int nt = 0; nt < 4; ++nt)
                #pragma unroll
                for (int r = 0; r < 4; ++r) cm = fmaxf(cm, sc[nt][r]);
            cm = fmaxf(cm, __shfl_xor(cm, 16));
            cm = fmaxf(cm, __shfl_xor(cm, 32));
            float mn = fmaxf(mi, cm);
            float so = __expf(mi - mn);
            mi = mn;
            float rs = 0.f;
            u32 dw0, dw1, dw2, dw3, dw4, dw5, dw6, dw7;
            {
                float p0, p1, p2, p3;
                p0 = __expf(sc[0][0] - mn); p1 = __expf(sc[0][1] - mn);
                p2 = __expf(sc[0][2] - mn); p3 = __expf(sc[0][3] - mn);
                rs += (p0 + p1) + (p2 + p3); dw0 = pkbf(p0, p1); dw1 = pkbf(p2, p3);
                p0 = __expf(sc[1][0] - mn); p1 = __expf(sc[1][1] - mn);
                p2 = __expf(sc[1][2] - mn); p3 = __expf(sc[1][3] - mn);
                rs += (p0 + p1) + (p2 + p3); dw2 = pkbf(p0, p1); dw3 = pkbf(p2, p3);
                p0 = __expf(sc[2][0] - mn); p1 = __expf(sc[2][1] - mn);
                p2 = __expf(sc[2][2] - mn); p3 = __expf(sc[2][3] - mn);
                rs += (p0 + p1) + (p2 + p3); dw4 = pkbf(p0, p1); dw5 = pkbf(p2, p3);
                p0 = __expf(sc[3][0] - mn); p1 = __expf(sc[3][1] - mn);
                p2 = __expf(sc[3][2] - mn); p3 = __expf(sc[3][3] - mn);
                rs += (p0 + p1) + (p2 + p3); dw6 = pkbf(p0, p1); dw7 = pkbf(p2, p3);
            }
            rs += __shfl_xor(rs, 16);
            rs += __shfl_xor(rs, 32);
            li = li * so + rs;
            float so0 = __shfl(so, lg * 4 + 0), so1 = __shfl(so, lg * 4 + 1);
            float so2 = __shfl(so, lg * 4 + 2), so3 = __shfl(so, lg * 4 + 3);
            #pragma unroll
            for (int d = 0; d < 4; ++d) {
                acc[d][0] *= so0; acc[d][1] *= so1;
                acc[d][2] *= so2; acc[d][3] *= so3;
            }
            bf16x8 pa0 = __builtin_bit_cast(bf16x8, make_int4((int)dw0, (int)dw1, (int)dw2, (int)dw3));
            bf16x8 pa1 = __builtin_bit_cast(bf16x8, make_int4((int)dw4, (int)dw5, (int)dw6, (int)dw7));
            #pragma unroll
            for (int d = 0; d < 4; ++d) {
                const u16* vrow = Vc[d * 16 + l15];
                int2 a0 = *(const int2*)(vrow + lg * 4);
                int2 a1 = *(const int2*)(vrow + 16 + lg * 4);
                int2 a2 = *(const int2*)(vrow + 32 + lg * 4);
                int2 a3 = *(const int2*)(vrow + 48 + lg * 4);
                bf16x8 vf0 = __builtin_bit_cast(bf16x8, make_int4(a0.x, a0.y, a1.x, a1.y));
                bf16x8 vf1 = __builtin_bit_cast(bf16x8, make_int4(a2.x, a2.y, a3.x, a3.y));
                acc[d] = __builtin_amdgcn_mfma_f32_16x16x32_bf16(pa0, vf0, acc[d], 0, 0, 0);
                acc[d] = __builtin_amdgcn_mfma_f32_16x16x32_bf16(pa1, vf1, acc[d], 0, 0, 0);
            }
        }
        if (jt < jmax) {
            *(int4*)&Ks[cur ^ 1][row][c8] = kn;
            *(int4*)&Vs[cur ^ 1][row][c8] = vn;
        }
        __syncthreads();
    }

    float il0 = 1.0f / __shfl(li, lg * 4 + 0);
    float il1 = 1.0f / __shfl(li, lg * 4 + 1);
    float il2 = 1.0f / __shfl(li, lg * 4 + 2);
    float il3 = 1.0f / __shfl(li, lg * 4 + 3);
    #pragma unroll
    for (int r = 0; r < 4; ++r) {
        float il = (r == 0) ? il0 : (r == 1) ? il1 : (r == 2) ? il2 : il3;
        int s = wrow0 + lg * 4 + r;
        size_t base = ((size_t)b * SEQ + s) * DM + h * HD;
        #pragma unroll
        for (int d = 0; d < 4; ++d)
            ctx[base + d * 16 + l15] = f2bf(acc[d][r] * il);
    }
}

extern "C" void kernel_launch(void* const* d_in, const int* in_sizes, int n_in,
                              void* d_out, int out_size, void* d_ws, size_t ws_size,
                              hipStream_t stream) {
    const float* x  = (const float*)d_in[0];
    const float* Wq = (const float*)d_in[1];
    const float* bq = (const float*)d_in[2];
    const float* Wk = (const float*)d_in[3];
    const float* bk = (const float*)d_in[4];
    const float* Wv = (const float*)d_in[5];
    const float* bv = (const float*)d_in[6];
    const float* Wo = (const float*)d_in[7];
    const float* bo = (const float*)d_in[8];
    float* out = (float*)d_out;

    char* ws = (char*)d_ws;
    u16* xb  = (u16*)(ws);                    // 8192*768*2      = 12,582,912
    u16* Wt  = (u16*)(ws + 12582912);         // 2304*768*2      =  3,538,944
    u16* Wto = (u16*)(ws + 16121856);         // 768*768*2       =  1,179,648
    u16* Qw  = (u16*)(ws + 17301504);         // [BH][S][64]     = 12,582,912
    u16* Kw  = (u16*)(ws + 29884416);         // [BH][S][64]     = 12,582,912
    u16* Vtw = (u16*)(ws + 42467328);         // [BH][64][S]     = 12,582,912
    u16* ctx = (u16*)(ws + 55050240);         // [B][S][768]     = 12,582,912

    cvt_x<<<6144, 256, 0, stream>>>(x, xb, NTOK * DM / 4);
    dim3 tb(32, 8), tg4(24, 24, 4);
    transpose_w4<<<tg4, tb, 0, stream>>>(Wq, Wk, Wv, Wo, Wt, Wto);

    dim3 g2(32, 9);
    gemm_pipe<0><<<g2, 512, 0, stream>>>(xb, Wt, bq, bk, bv, Qw, Kw, Vtw, nullptr);
    attn_fwd<<<768, 512, 0, stream>>>(Qw, Kw, Vtw, ctx);
    dim3 g4(64, 4);
    gemm_pipe<1><<<g4, 512, 0, stream>>>(ctx, Wto, bo, nullptr, nullptr, nullptr, nullptr, nullptr, out);
}

// Round 7
// 156.366 us; speedup vs baseline: 1.7337x; 1.0247x over previous
//
#include <hip/hip_runtime.h>
#include <stdint.h>

#define DM    768
#define NH    12
#define HD    64
#define BATCH 4
#define SEQ   2048
#define NTOK  (BATCH*SEQ)   // 8192
#define NKT   12            // 768 / 64 K-tiles

typedef unsigned int   u32;
typedef unsigned short u16;
using bf16x8 = __attribute__((ext_vector_type(8))) short;
using f32x4  = __attribute__((ext_vector_type(4))) float;

// softmax runs in exp2 domain: Q pre-scaled by (1/8)*log2(e)
#define QSCALE 0.18033688011112042f

__device__ __forceinline__ u16 f2bf(float f) {
    u32 u = __float_as_uint(f);
    u = (u + 0x7FFFu + ((u >> 16) & 1u)) >> 16;
    return (u16)u;
}

__device__ __forceinline__ u32 pkbf(float a, float b) {
    u32 r;
    asm("v_cvt_pk_bf16_f32 %0, %1, %2" : "=v"(r) : "v"(a), "v"(b));
    return r;
}

template <int N>
__device__ __forceinline__ void waitvm() {
    if constexpr (N == 0)      asm volatile("s_waitcnt vmcnt(0)" ::: "memory");
    else if constexpr (N == 5) asm volatile("s_waitcnt vmcnt(5)" ::: "memory");
    else if constexpr (N == 8) asm volatile("s_waitcnt vmcnt(8)" ::: "memory");
    else                       static_assert(N == 0 || N == 5 || N == 8, "add literal");
}

__device__ __forceinline__ void gload_lds16(const void* gptr, void* ldsptr) {
    __builtin_amdgcn_global_load_lds(
        (__attribute__((address_space(1))) const u32*)gptr,
        (__attribute__((address_space(3))) u32*)ldsptr, 16, 0, 0);
}

__device__ __forceinline__ float vmax4(f32x4 v) {
    return fmaxf(fmaxf(v[0], v[1]), fmaxf(v[2], v[3]));
}

// ---------------- x fp32 -> bf16 (vectorized) ----------------
__global__ void cvt_x(const float* __restrict__ x, u16* __restrict__ xb, int n4) {
    int i = blockIdx.x * blockDim.x + threadIdx.x;
    if (i >= n4) return;
    float4 v = ((const float4*)x)[i];
    ushort4 o;
    o.x = f2bf(v.x); o.y = f2bf(v.y); o.z = f2bf(v.z); o.w = f2bf(v.w);
    ((ushort4*)xb)[i] = o;
}

// ------- all 4 weight transposes in ONE launch: W [k][n] fp32 -> Wt [n][k] bf16 -------
__global__ void transpose_w4(const float* __restrict__ q, const float* __restrict__ k,
                             const float* __restrict__ v, const float* __restrict__ o,
                             u16* __restrict__ Wt, u16* __restrict__ Wto) {
    __shared__ float tile[32][33];
    int z = blockIdx.z;
    const float* W = (z == 0) ? q : (z == 1) ? k : (z == 2) ? v : o;
    u16* D = (z < 3) ? (Wt + (size_t)z * DM * DM) : Wto;
    int tx = threadIdx.x, ty = threadIdx.y;   // 32 x 8
    int x0 = blockIdx.x * 32, y0 = blockIdx.y * 32;
    #pragma unroll
    for (int i = 0; i < 32; i += 8)
        tile[ty + i][tx] = W[(size_t)(y0 + ty + i) * DM + x0 + tx];
    __syncthreads();
    #pragma unroll
    for (int i = 0; i < 32; i += 8)
        D[(size_t)(x0 + ty + i) * DM + y0 + tx] = f2bf(tile[tx][ty + i]);
}

// ---- bf16 MFMA GEMM, BK=64, 2-tiles-ahead pipeline with counted vmcnt (T3/T4) ----
template <int MODE>
__global__ __launch_bounds__(512, 2)
void gemm_pipe(const u16* __restrict__ A, const u16* __restrict__ Bt,
               const float* __restrict__ b0, const float* __restrict__ b1,
               const float* __restrict__ b2,
               u16* __restrict__ Qo, u16* __restrict__ Ko, u16* __restrict__ Vto,
               float* __restrict__ Out)
{
    constexpr int BM = (MODE == 0) ? 256 : 128;
    constexpr int BN = (MODE == 0) ? 256 : 192;
    constexpr int MF = BM / 32;
    constexpr int NF = BN / 64;
    constexpr int AL = BM / 64;
    constexpr int BL = BN / 64;
    constexpr int TL = AL + BL;

    __shared__ u16 As[2][BM][64];
    __shared__ u16 Bs[2][BN][64];

    const int t = threadIdx.x;
    const int w = t >> 6, l = t & 63;
    const int l15 = l & 15, lg = l >> 4;
    const int m0 = blockIdx.x * BM;
    const int n0 = blockIdx.y * BN;
    const int waveM = (w >> 2) * (BM / 2);
    const int waveN = (w & 3) * (BN / 4);

    f32x4 zf = {0.f, 0.f, 0.f, 0.f};
    f32x4 acc[MF][NF];
    #pragma unroll
    for (int i = 0; i < MF; ++i)
        #pragma unroll
        for (int j = 0; j < NF; ++j) acc[i][j] = zf;

    const u16* Arow0 = A  + (size_t)m0 * DM;
    const u16* Brow0 = Bt + (size_t)n0 * DM;

    auto stage = [&](int d, int k0) {
        #pragma unroll
        for (int i = 0; i < AL; ++i) {
            int f = i * 512 + t;
            int row = f >> 3, c = f & 7;
            int gc = c ^ (row & 7);
            gload_lds16(Arow0 + (size_t)row * DM + k0 + gc * 8, &As[d][row][c * 8]);
        }
        #pragma unroll
        for (int i = 0; i < BL; ++i) {
            int f = i * 512 + t;
            int row = f >> 3, c = f & 7;
            int gc = c ^ (row & 7);
            gload_lds16(Brow0 + (size_t)row * DM + k0 + gc * 8, &Bs[d][row][c * 8]);
        }
    };
    auto phase = [&](int d, int kk) {
        const int ch = ((kk * 4 + lg) ^ (l15 & 7)) * 8;
        bf16x8 af[MF], bfr[NF];
        #pragma unroll
        for (int m = 0; m < MF; ++m)
            af[m] = *(const bf16x8*)&As[d][waveM + m * 16 + l15][ch];
        #pragma unroll
        for (int n = 0; n < NF; ++n)
            bfr[n] = *(const bf16x8*)&Bs[d][waveN + n * 16 + l15][ch];
        __builtin_amdgcn_s_setprio(1);
        #pragma unroll
        for (int m = 0; m < MF; ++m)
            #pragma unroll
            for (int n = 0; n < NF; ++n)
                acc[m][n] = __builtin_amdgcn_mfma_f32_16x16x32_bf16(af[m], bfr[n], acc[m][n], 0, 0, 0);
        __builtin_amdgcn_s_setprio(0);
    };

    stage(0, 0);
    stage(1, 64);

    for (int tt = 0; tt < NKT - 1; ++tt) {
        const int c = tt & 1;
        waitvm<TL>();
        __builtin_amdgcn_s_barrier();
        __builtin_amdgcn_sched_barrier(0);
        phase(c, 0);
        phase(c, 1);
        __builtin_amdgcn_sched_barrier(0);
        __builtin_amdgcn_s_barrier();
        __builtin_amdgcn_sched_barrier(0);
        if (tt + 2 < NKT) stage(c, (tt + 2) * 64);
    }
    {
        waitvm<0>();
        __builtin_amdgcn_s_barrier();
        __builtin_amdgcn_sched_barrier(0);
        phase((NKT - 1) & 1, 0);
        phase((NKT - 1) & 1, 1);
    }

    if (MODE == 1) {
        #pragma unroll
        for (int m = 0; m < MF; ++m) {
            int grow = m0 + waveM + m * 16 + lg * 4;
            #pragma unroll
            for (int n = 0; n < NF; ++n) {
                int gcol = n0 + waveN + n * 16 + l15;
                float bias = b0[gcol];
                #pragma unroll
                for (int r = 0; r < 4; ++r)
                    Out[(size_t)(grow + r) * DM + gcol] = acc[m][n][r] + bias;
            }
        }
    } else {
        const int which = n0 / DM;
        #pragma unroll
        for (int m = 0; m < MF; ++m) {
            int grow = m0 + waveM + m * 16 + lg * 4;
            int bb = grow >> 11, ss = grow & 2047;
            #pragma unroll
            for (int n = 0; n < NF; ++n) {
                int gcol = n0 + waveN + n * 16 + l15;
                int cc = gcol - which * DM;
                int h = cc >> 6, hd = cc & 63;
                if (which == 0) {
                    float bias = b0[cc];
                    #pragma unroll
                    for (int r = 0; r < 4; ++r)
                        Qo[(((size_t)bb * NH + h) * SEQ + (ss + r)) * HD + hd] =
                            f2bf((acc[m][n][r] + bias) * QSCALE);
                } else if (which == 1) {
                    float bias = b1[cc];
                    #pragma unroll
                    for (int r = 0; r < 4; ++r)
                        Ko[(((size_t)bb * NH + h) * SEQ + (ss + r)) * HD + hd] =
                            f2bf(acc[m][n][r] + bias);
                } else {
                    float bias = b2[cc];
                    u32 lo = pkbf(acc[m][n][0] + bias, acc[m][n][1] + bias);
                    u32 hi = pkbf(acc[m][n][2] + bias, acc[m][n][3] + bias);
                    *(int2*)&Vto[(((size_t)bb * NH + h) * HD + hd) * SEQ + ss] =
                        make_int2((int)lo, (int)hi);
                }
            }
        }
    }
}

// ---------------- causal flash attention v3 ----------------
// 8 waves x 32 q-rows = 256 rows/block (two 16-col Q fragments per wave share
// every K/V LDS fragment -> per-work LDS traffic, staging, barriers halve).
// exp2-domain softmax (Q pre-scaled by log2e/8), defer-max (THR=8, T13),
// double-buffered KV, issue-early/write-late, setprio (T5).
__global__ __launch_bounds__(512, 3)
void attn_fwd(const u16* __restrict__ Q, const u16* __restrict__ K_,
              const u16* __restrict__ Vt, u16* __restrict__ ctx)
{
    __shared__ u16 Ks[2][64][72];
    __shared__ u16 Vs[2][64][72];

    const int t = threadIdx.x, w = t >> 6, l = t & 63;
    const int l15 = l & 15, lg = l >> 4;
    const int bx = blockIdx.x;
    const int ord = bx / 48;            // ascending => q8 descending (LPT dispatch)
    const int bh  = bx - ord * 48;
    const int q8  = 7 - ord;            // 256-row block index
    const int b = bh / NH, h = bh - b * NH;
    const int wrow0 = q8 * 256 + w * 32;
    const int jmax = 4 * q8 + 3;

    const u16* Qp0 = Q + ((size_t)bh * SEQ + wrow0 + l15) * HD;
    const u16* Qp1 = Qp0 + 16 * HD;
    bf16x8 qf00 = *(const bf16x8*)(Qp0 + lg * 8);
    bf16x8 qf01 = *(const bf16x8*)(Qp0 + 32 + lg * 8);
    bf16x8 qf10 = *(const bf16x8*)(Qp1 + lg * 8);
    bf16x8 qf11 = *(const bf16x8*)(Qp1 + 32 + lg * 8);

    f32x4 zf = {0.f, 0.f, 0.f, 0.f};
    f32x4 acc0[4], acc1[4];
    #pragma unroll
    for (int d = 0; d < 4; ++d) { acc0[d] = zf; acc1[d] = zf; }
    float mi0 = -INFINITY, li0 = 0.f;   // stats for q = wrow0 + l15      (qc 0)
    float mi1 = -INFINITY, li1 = 0.f;   // stats for q = wrow0 + 16 + l15 (qc 1)

    const u16* Kbh = K_ + (size_t)bh * SEQ * HD;
    const u16* Vbh = Vt + (size_t)bh * HD * SEQ;
    const int row = t >> 3, c8 = (t & 7) * 8;   // 512 thr x 1 int4 = full 64x64 tile

    {
        int4 kr = *(const int4*)(Kbh + (size_t)row * HD + c8);
        int4 vr = *(const int4*)(Vbh + (size_t)row * SEQ + c8);
        *(int4*)&Ks[0][row][c8] = kr;
        *(int4*)&Vs[0][row][c8] = vr;
    }
    __syncthreads();

    for (int jt = 0; jt <= jmax; ++jt) {
        const int cur = jt & 1;
        const int j0 = jt << 6;
        int4 kn, vn;
        if (jt < jmax) {                // issue next-tile loads early
            int j1 = j0 + 64;
            kn = *(const int4*)(Kbh + (size_t)(j1 + row) * HD + c8);
            vn = *(const int4*)(Vbh + (size_t)row * SEQ + j1 + c8);
        }
        if (j0 <= wrow0 + 31) {         // wave-uniform causal skip
            const u16 (*Kc)[72] = Ks[cur];
            const u16 (*Vc)[72] = Vs[cur];
            // S^T: rows = keys (lg*4+r), cols = q (l15), two q-column frags
            f32x4 s0[4], s1[4];
            __builtin_amdgcn_s_setprio(1);
            #pragma unroll
            for (int nt = 0; nt < 4; ++nt) {
                bf16x8 kf0 = *(const bf16x8*)&Kc[nt * 16 + l15][lg * 8];
                bf16x8 kf1 = *(const bf16x8*)&Kc[nt * 16 + l15][32 + lg * 8];
                f32x4 a = zf;
                a = __builtin_amdgcn_mfma_f32_16x16x32_bf16(kf0, qf00, a, 0, 0, 0);
                a = __builtin_amdgcn_mfma_f32_16x16x32_bf16(kf1, qf01, a, 0, 0, 0);
                s0[nt] = a;
                f32x4 c2 = zf;
                c2 = __builtin_amdgcn_mfma_f32_16x16x32_bf16(kf0, qf10, c2, 0, 0, 0);
                c2 = __builtin_amdgcn_mfma_f32_16x16x32_bf16(kf1, qf11, c2, 0, 0, 0);
                s1[nt] = c2;
            }
            __builtin_amdgcn_s_setprio(0);
            if (j0 + 63 > wrow0) {      // diagonal region: per-element causal mask
                #pragma unroll
                for (int nt = 0; nt < 4; ++nt) {
                    int kb = j0 + nt * 16 + lg * 4;
                    #pragma unroll
                    for (int r = 0; r < 4; ++r) {
                        if (kb + r > wrow0 + l15)      s0[nt][r] = -INFINITY;
                        if (kb + r > wrow0 + 16 + l15) s1[nt][r] = -INFINITY;
                    }
                }
            }
            // per-row tile max (key axis lane-local + 2 cross-lg shuffles)
            float pm0 = fmaxf(fmaxf(vmax4(s0[0]), vmax4(s0[1])), fmaxf(vmax4(s0[2]), vmax4(s0[3])));
            float pm1 = fmaxf(fmaxf(vmax4(s1[0]), vmax4(s1[1])), fmaxf(vmax4(s1[2]), vmax4(s1[3])));
            pm0 = fmaxf(pm0, __shfl_xor(pm0, 16)); pm0 = fmaxf(pm0, __shfl_xor(pm0, 32));
            pm1 = fmaxf(pm1, __shfl_xor(pm1, 16)); pm1 = fmaxf(pm1, __shfl_xor(pm1, 32));
            // defer-max: skip rescale while max grows < 8 (exp2 domain: p <= 256)
            if (!__all((pm0 <= mi0 + 8.f) && (pm1 <= mi1 + 8.f))) {
                float mn0 = fmaxf(mi0, pm0), mn1 = fmaxf(mi1, pm1);
                float so0 = __builtin_amdgcn_exp2f(mi0 - mn0);   // first tile: 0
                float so1 = __builtin_amdgcn_exp2f(mi1 - mn1);
                mi0 = mn0; mi1 = mn1;
                li0 *= so0; li1 *= so1;
                float a0 = __shfl(so0, lg * 4 + 0), a1 = __shfl(so0, lg * 4 + 1);
                float a2 = __shfl(so0, lg * 4 + 2), a3 = __shfl(so0, lg * 4 + 3);
                float b0_ = __shfl(so1, lg * 4 + 0), b1_ = __shfl(so1, lg * 4 + 1);
                float b2_ = __shfl(so1, lg * 4 + 2), b3_ = __shfl(so1, lg * 4 + 3);
                #pragma unroll
                for (int d = 0; d < 4; ++d) {
                    acc0[d][0] *= a0;  acc0[d][1] *= a1;  acc0[d][2] *= a2;  acc0[d][3] *= a3;
                    acc1[d][0] *= b0_; acc1[d][1] *= b1_; acc1[d][2] *= b2_; acc1[d][3] *= b3_;
                }
            }
            // p = exp2(s - mi), pack to bf16 in-register
            u32 dwa[8], dwb[8];
            float rs0 = 0.f, rs1 = 0.f;
            #pragma unroll
            for (int nt = 0; nt < 4; ++nt) {
                float p0 = __builtin_amdgcn_exp2f(s0[nt][0] - mi0);
                float p1 = __builtin_amdgcn_exp2f(s0[nt][1] - mi0);
                float p2 = __builtin_amdgcn_exp2f(s0[nt][2] - mi0);
                float p3 = __builtin_amdgcn_exp2f(s0[nt][3] - mi0);
                rs0 += (p0 + p1) + (p2 + p3);
                dwa[nt * 2] = pkbf(p0, p1); dwa[nt * 2 + 1] = pkbf(p2, p3);
                float q0 = __builtin_amdgcn_exp2f(s1[nt][0] - mi1);
                float q1 = __builtin_amdgcn_exp2f(s1[nt][1] - mi1);
                float q2 = __builtin_amdgcn_exp2f(s1[nt][2] - mi1);
                float q3 = __builtin_amdgcn_exp2f(s1[nt][3] - mi1);
                rs1 += (q0 + q1) + (q2 + q3);
                dwb[nt * 2] = pkbf(q0, q1); dwb[nt * 2 + 1] = pkbf(q2, q3);
            }
            rs0 += __shfl_xor(rs0, 16); rs0 += __shfl_xor(rs0, 32);
            rs1 += __shfl_xor(rs1, 16); rs1 += __shfl_xor(rs1, 32);
            li0 += rs0; li1 += rs1;
            bf16x8 pa00 = __builtin_bit_cast(bf16x8, make_int4((int)dwa[0], (int)dwa[1], (int)dwa[2], (int)dwa[3]));
            bf16x8 pa01 = __builtin_bit_cast(bf16x8, make_int4((int)dwa[4], (int)dwa[5], (int)dwa[6], (int)dwa[7]));
            bf16x8 pa10 = __builtin_bit_cast(bf16x8, make_int4((int)dwb[0], (int)dwb[1], (int)dwb[2], (int)dwb[3]));
            bf16x8 pa11 = __builtin_bit_cast(bf16x8, make_int4((int)dwb[4], (int)dwb[5], (int)dwb[6], (int)dwb[7]));
            // O += P V (V fragments shared by both q-column frags)
            __builtin_amdgcn_s_setprio(1);
            #pragma unroll
            for (int d = 0; d < 4; ++d) {
                const u16* vrow = Vc[d * 16 + l15];
                int2 v0 = *(const int2*)(vrow + lg * 4);
                int2 v1 = *(const int2*)(vrow + 16 + lg * 4);
                int2 v2 = *(const int2*)(vrow + 32 + lg * 4);
                int2 v3 = *(const int2*)(vrow + 48 + lg * 4);
                bf16x8 vf0 = __builtin_bit_cast(bf16x8, make_int4(v0.x, v0.y, v1.x, v1.y));
                bf16x8 vf1 = __builtin_bit_cast(bf16x8, make_int4(v2.x, v2.y, v3.x, v3.y));
                acc0[d] = __builtin_amdgcn_mfma_f32_16x16x32_bf16(pa00, vf0, acc0[d], 0, 0, 0);
                acc0[d] = __builtin_amdgcn_mfma_f32_16x16x32_bf16(pa01, vf1, acc0[d], 0, 0, 0);
                acc1[d] = __builtin_amdgcn_mfma_f32_16x16x32_bf16(pa10, vf0, acc1[d], 0, 0, 0);
                acc1[d] = __builtin_amdgcn_mfma_f32_16x16x32_bf16(pa11, vf1, acc1[d], 0, 0, 0);
            }
            __builtin_amdgcn_s_setprio(0);
        }
        if (jt < jmax) {                // write-late into the other buffer
            *(int4*)&Ks[cur ^ 1][row][c8] = kn;
            *(int4*)&Vs[cur ^ 1][row][c8] = vn;
        }
        __syncthreads();
    }

    // epilogue: ctx [B][S][768] bf16
    float e00 = 1.0f / __shfl(li0, lg * 4 + 0), e01 = 1.0f / __shfl(li0, lg * 4 + 1);
    float e02 = 1.0f / __shfl(li0, lg * 4 + 2), e03 = 1.0f / __shfl(li0, lg * 4 + 3);
    float e10 = 1.0f / __shfl(li1, lg * 4 + 0), e11 = 1.0f / __shfl(li1, lg * 4 + 1);
    float e12 = 1.0f / __shfl(li1, lg * 4 + 2), e13 = 1.0f / __shfl(li1, lg * 4 + 3);
    #pragma unroll
    for (int r = 0; r < 4; ++r) {
        float f0 = (r == 0) ? e00 : (r == 1) ? e01 : (r == 2) ? e02 : e03;
        float f1 = (r == 0) ? e10 : (r == 1) ? e11 : (r == 2) ? e12 : e13;
        int s0r = wrow0 + lg * 4 + r;
        size_t base0 = ((size_t)b * SEQ + s0r) * DM + h * HD;
        size_t base1 = ((size_t)b * SEQ + s0r + 16) * DM + h * HD;
        #pragma unroll
        for (int d = 0; d < 4; ++d) {
            ctx[base0 + d * 16 + l15] = f2bf(acc0[d][r] * f0);
            ctx[base1 + d * 16 + l15] = f2bf(acc1[d][r] * f1);
        }
    }
}

extern "C" void kernel_launch(void* const* d_in, const int* in_sizes, int n_in,
                              void* d_out, int out_size, void* d_ws, size_t ws_size,
                              hipStream_t stream) {
    const float* x  = (const float*)d_in[0];
    const float* Wq = (const float*)d_in[1];
    const float* bq = (const float*)d_in[2];
    const float* Wk = (const float*)d_in[3];
    const float* bk = (const float*)d_in[4];
    const float* Wv = (const float*)d_in[5];
    const float* bv = (const float*)d_in[6];
    const float* Wo = (const float*)d_in[7];
    const float* bo = (const float*)d_in[8];
    float* out = (float*)d_out;

    char* ws = (char*)d_ws;
    u16* xb  = (u16*)(ws);                    // 8192*768*2      = 12,582,912
    u16* Wt  = (u16*)(ws + 12582912);         // 2304*768*2      =  3,538,944
    u16* Wto = (u16*)(ws + 16121856);         // 768*768*2       =  1,179,648
    u16* Qw  = (u16*)(ws + 17301504);         // [BH][S][64]     = 12,582,912
    u16* Kw  = (u16*)(ws + 29884416);         // [BH][S][64]     = 12,582,912
    u16* Vtw = (u16*)(ws + 42467328);         // [BH][64][S]     = 12,582,912
    u16* ctx = (u16*)(ws + 55050240);         // [B][S][768]     = 12,582,912

    cvt_x<<<6144, 256, 0, stream>>>(x, xb, NTOK * DM / 4);
    dim3 tb(32, 8), tg4(24, 24, 4);
    transpose_w4<<<tg4, tb, 0, stream>>>(Wq, Wk, Wv, Wo, Wt, Wto);

    dim3 g2(32, 9);
    gemm_pipe<0><<<g2, 512, 0, stream>>>(xb, Wt, bq, bk, bv, Qw, Kw, Vtw, nullptr);
    attn_fwd<<<384, 512, 0, stream>>>(Qw, Kw, Vtw, ctx);
    dim3 g4(64, 4);
    gemm_pipe<1><<<g4, 512, 0, stream>>>(ctx, Wto, bo, nullptr, nullptr, nullptr, nullptr, nullptr, out);
}

// Round 8
// 132.023 us; speedup vs baseline: 2.0533x; 1.1844x over previous
//
#include <hip/hip_runtime.h>
#include <stdint.h>

#define DM    768
#define NH    12
#define HD    64
#define BATCH 4
#define SEQ   2048
#define NTOK  (BATCH*SEQ)   // 8192
#define NKT   12            // 768 / 64 K-tiles

typedef unsigned int   u32;
typedef unsigned short u16;
using bf16x8 = __attribute__((ext_vector_type(8))) short;
using f32x4  = __attribute__((ext_vector_type(4))) float;

// softmax runs in exp2 domain: Q pre-scaled by (1/8)*log2(e)
#define QSCALE 0.18033688011112042f

__device__ __forceinline__ u16 f2bf(float f) {
    u32 u = __float_as_uint(f);
    u = (u + 0x7FFFu + ((u >> 16) & 1u)) >> 16;
    return (u16)u;
}

__device__ __forceinline__ u32 pkbf(float a, float b) {
    u32 r;
    asm("v_cvt_pk_bf16_f32 %0, %1, %2" : "=v"(r) : "v"(a), "v"(b));
    return r;
}

template <int N>
__device__ __forceinline__ void waitvm() {
    if constexpr (N == 0)      asm volatile("s_waitcnt vmcnt(0)" ::: "memory");
    else if constexpr (N == 5) asm volatile("s_waitcnt vmcnt(5)" ::: "memory");
    else if constexpr (N == 8) asm volatile("s_waitcnt vmcnt(8)" ::: "memory");
    else if constexpr (N == 9) asm volatile("s_waitcnt vmcnt(9)" ::: "memory");
    else                       static_assert(N == 0 || N == 5 || N == 8 || N == 9, "add literal");
}

__device__ __forceinline__ void gload_lds16(const void* gptr, void* ldsptr) {
    __builtin_amdgcn_global_load_lds(
        (__attribute__((address_space(1))) const u32*)gptr,
        (__attribute__((address_space(3))) u32*)ldsptr, 16, 0, 0);
}

__device__ __forceinline__ float vmax4(f32x4 v) {
    return fmaxf(fmaxf(v[0], v[1]), fmaxf(v[2], v[3]));
}

// ---------------- x fp32 -> bf16 (vectorized) ----------------
__global__ void cvt_x(const float* __restrict__ x, u16* __restrict__ xb, int n4) {
    int i = blockIdx.x * blockDim.x + threadIdx.x;
    if (i >= n4) return;
    float4 v = ((const float4*)x)[i];
    ushort4 o;
    o.x = f2bf(v.x); o.y = f2bf(v.y); o.z = f2bf(v.z); o.w = f2bf(v.w);
    ((ushort4*)xb)[i] = o;
}

// ------- all 4 weight transposes in ONE launch: W [k][n] fp32 -> Wt [n][k] bf16 -------
__global__ void transpose_w4(const float* __restrict__ q, const float* __restrict__ k,
                             const float* __restrict__ v, const float* __restrict__ o,
                             u16* __restrict__ Wt, u16* __restrict__ Wto) {
    __shared__ float tile[32][33];
    int z = blockIdx.z;
    const float* W = (z == 0) ? q : (z == 1) ? k : (z == 2) ? v : o;
    u16* D = (z < 3) ? (Wt + (size_t)z * DM * DM) : Wto;
    int tx = threadIdx.x, ty = threadIdx.y;   // 32 x 8
    int x0 = blockIdx.x * 32, y0 = blockIdx.y * 32;
    #pragma unroll
    for (int i = 0; i < 32; i += 8)
        tile[ty + i][tx] = W[(size_t)(y0 + ty + i) * DM + x0 + tx];
    __syncthreads();
    #pragma unroll
    for (int i = 0; i < 32; i += 8)
        D[(size_t)(x0 + ty + i) * DM + y0 + tx] = f2bf(tile[tx][ty + i]);
}

// ---- bf16 MFMA GEMM, BK=64, 2-tiles-ahead pipeline with counted vmcnt (T3/T4) ----
// 8 waves (512 thr).
// MODE 0: BM=256, BN=288, grid 32x8 = EXACTLY 256 blocks (1/CU, zero tail).
//         Wave layout 4Mx2N: waveM=64 (MF=4), waveN=144 (NF=9).
//         A=xb[8192][768], Bt=Wqkv^T[2304][768] -> Q(scaled)/K [BH][S][64], V^T [BH][64][S]
// MODE 1: BM=128, BN=192, grid 64x4 = 256 blocks. 2Mx4N: MF=4, NF=3.
//         A=ctx[8192][768], Bt=Wo^T[768][768]   -> Out fp32 [8192][768] + bias
// LDS XOR swizzle: LDS chunk c of row r holds global chunk c ^ (r&7); readers
// fetch chunk (kk*4+lg) ^ (l15&7)  (both-sides involution, rule #21).
// Pipeline: tiles t and t+1 always in flight; iter t waits vmcnt(TL) (tile t
// done, t+1 still flying), computes both phases (no mid-barrier), then stages
// tile t+2 into the freed buffer. vmcnt(0) only on the final tile.
// MODE0 B staging = 4.5 chunks/thread: 4 full rounds + waves 0-3 one extra,
// so TL is per-wave (9 for waves 0-3, 8 for waves 4-7) - wave-uniform branch.
template <int MODE>
__global__ __launch_bounds__(512, 2)
void gemm_pipe(const u16* __restrict__ A, const u16* __restrict__ Bt,
               const float* __restrict__ b0, const float* __restrict__ b1,
               const float* __restrict__ b2,
               u16* __restrict__ Qo, u16* __restrict__ Ko, u16* __restrict__ Vto,
               float* __restrict__ Out)
{
    constexpr int BM = (MODE == 0) ? 256 : 128;
    constexpr int BN = (MODE == 0) ? 288 : 192;
    constexpr int MF = 4;
    constexpr int NF = (MODE == 0) ? 9 : 3;
    constexpr int AL = BM / 64;                 // per-thread A chunks (4 / 2)
    constexpr int BFULL = (MODE == 0) ? 4 : 3;  // full-coverage B chunk rounds

    __shared__ u16 As[2][BM][64];
    __shared__ u16 Bs[2][BN][64];

    const int t = threadIdx.x;
    const int w = t >> 6, l = t & 63;
    const int l15 = l & 15, lg = l >> 4;
    const int m0 = blockIdx.x * BM;
    const int n0 = blockIdx.y * BN;
    const int waveM = ((MODE == 0) ? (w >> 1) : (w >> 2)) * 64;
    const int waveN = (MODE == 0) ? (w & 1) * 144 : (w & 3) * 48;

    f32x4 zf = {0.f, 0.f, 0.f, 0.f};
    f32x4 acc[MF][NF];
    #pragma unroll
    for (int i = 0; i < MF; ++i)
        #pragma unroll
        for (int j = 0; j < NF; ++j) acc[i][j] = zf;

    const u16* Arow0 = A  + (size_t)m0 * DM;
    const u16* Brow0 = Bt + (size_t)n0 * DM;

    auto stage = [&](int d, int k0) {
        #pragma unroll
        for (int i = 0; i < AL; ++i) {
            int f = i * 512 + t;
            int row = f >> 3, c = f & 7;
            int gc = c ^ (row & 7);
            gload_lds16(Arow0 + (size_t)row * DM + k0 + gc * 8, &As[d][row][c * 8]);
        }
        #pragma unroll
        for (int i = 0; i < BFULL; ++i) {
            int f = i * 512 + t;
            int row = f >> 3, c = f & 7;
            int gc = c ^ (row & 7);
            gload_lds16(Brow0 + (size_t)row * DM + k0 + gc * 8, &Bs[d][row][c * 8]);
        }
        if constexpr (MODE == 0) {
            if (t < 256) {                       // waves 0-3: rows 256..287
                int f = 2048 + t;
                int row = f >> 3, c = f & 7;
                int gc = c ^ (row & 7);
                gload_lds16(Brow0 + (size_t)row * DM + k0 + gc * 8, &Bs[d][row][c * 8]);
            }
        }
    };
    auto wait_tile = [&]() {                     // tile t done, tile t+1 in flight
        if constexpr (MODE == 0) {
            if (w < 4) waitvm<9>(); else waitvm<8>();
        } else {
            waitvm<5>();
        }
    };
    auto phase = [&](int d, int kk) {
        const int ch = ((kk * 4 + lg) ^ (l15 & 7)) * 8;
        bf16x8 af[MF], bfr[NF];
        #pragma unroll
        for (int m = 0; m < MF; ++m)
            af[m] = *(const bf16x8*)&As[d][waveM + m * 16 + l15][ch];
        #pragma unroll
        for (int n = 0; n < NF; ++n)
            bfr[n] = *(const bf16x8*)&Bs[d][waveN + n * 16 + l15][ch];
        __builtin_amdgcn_s_setprio(1);
        #pragma unroll
        for (int m = 0; m < MF; ++m)
            #pragma unroll
            for (int n = 0; n < NF; ++n)
                acc[m][n] = __builtin_amdgcn_mfma_f32_16x16x32_bf16(af[m], bfr[n], acc[m][n], 0, 0, 0);
        __builtin_amdgcn_s_setprio(0);
    };

    stage(0, 0);
    stage(1, 64);

    for (int tt = 0; tt < NKT - 1; ++tt) {
        const int c = tt & 1;
        wait_tile();
        __builtin_amdgcn_s_barrier();
        __builtin_amdgcn_sched_barrier(0);
        phase(c, 0);
        phase(c, 1);
        __builtin_amdgcn_sched_barrier(0);
        __builtin_amdgcn_s_barrier();
        __builtin_amdgcn_sched_barrier(0);
        if (tt + 2 < NKT) stage(c, (tt + 2) * 64);
    }
    {
        waitvm<0>();
        __builtin_amdgcn_s_barrier();
        __builtin_amdgcn_sched_barrier(0);
        phase((NKT - 1) & 1, 0);
        phase((NKT - 1) & 1, 1);
    }

    if (MODE == 1) {
        #pragma unroll
        for (int m = 0; m < MF; ++m) {
            int grow = m0 + waveM + m * 16 + lg * 4;
            #pragma unroll
            for (int n = 0; n < NF; ++n) {
                int gcol = n0 + waveN + n * 16 + l15;
                float bias = b0[gcol];
                #pragma unroll
                for (int r = 0; r < 4; ++r)
                    Out[(size_t)(grow + r) * DM + gcol] = acc[m][n][r] + bias;
            }
        }
    } else {
        #pragma unroll
        for (int m = 0; m < MF; ++m) {
            int grow = m0 + waveM + m * 16 + lg * 4;
            int bb = grow >> 11, ss = grow & 2047;
            #pragma unroll
            for (int n = 0; n < NF; ++n) {
                int nstart = n0 + waveN + n * 16;     // 16-aligned: which uniform per frag
                int which = nstart / DM;
                int cbase = nstart - which * DM + l15;
                int h = cbase >> 6, hd = cbase & 63;
                if (which == 0) {
                    float bias = b0[cbase];
                    #pragma unroll
                    for (int r = 0; r < 4; ++r)
                        Qo[(((size_t)bb * NH + h) * SEQ + (ss + r)) * HD + hd] =
                            f2bf((acc[m][n][r] + bias) * QSCALE);
                } else if (which == 1) {
                    float bias = b1[cbase];
                    #pragma unroll
                    for (int r = 0; r < 4; ++r)
                        Ko[(((size_t)bb * NH + h) * SEQ + (ss + r)) * HD + hd] =
                            f2bf(acc[m][n][r] + bias);
                } else {
                    float bias = b2[cbase];
                    u32 lo = pkbf(acc[m][n][0] + bias, acc[m][n][1] + bias);
                    u32 hi = pkbf(acc[m][n][2] + bias, acc[m][n][3] + bias);
                    *(int2*)&Vto[(((size_t)bb * NH + h) * HD + hd) * SEQ + ss] =
                        make_int2((int)lo, (int)hi);
                }
            }
        }
    }
}

// ---------------- causal flash attention v3 (unchanged from round 7) ----------------
__global__ __launch_bounds__(512, 3)
void attn_fwd(const u16* __restrict__ Q, const u16* __restrict__ K_,
              const u16* __restrict__ Vt, u16* __restrict__ ctx)
{
    __shared__ u16 Ks[2][64][72];
    __shared__ u16 Vs[2][64][72];

    const int t = threadIdx.x, w = t >> 6, l = t & 63;
    const int l15 = l & 15, lg = l >> 4;
    const int bx = blockIdx.x;
    const int ord = bx / 48;            // ascending => q8 descending (LPT dispatch)
    const int bh  = bx - ord * 48;
    const int q8  = 7 - ord;            // 256-row block index
    const int b = bh / NH, h = bh - b * NH;
    const int wrow0 = q8 * 256 + w * 32;
    const int jmax = 4 * q8 + 3;

    const u16* Qp0 = Q + ((size_t)bh * SEQ + wrow0 + l15) * HD;
    const u16* Qp1 = Qp0 + 16 * HD;
    bf16x8 qf00 = *(const bf16x8*)(Qp0 + lg * 8);
    bf16x8 qf01 = *(const bf16x8*)(Qp0 + 32 + lg * 8);
    bf16x8 qf10 = *(const bf16x8*)(Qp1 + lg * 8);
    bf16x8 qf11 = *(const bf16x8*)(Qp1 + 32 + lg * 8);

    f32x4 zf = {0.f, 0.f, 0.f, 0.f};
    f32x4 acc0[4], acc1[4];
    #pragma unroll
    for (int d = 0; d < 4; ++d) { acc0[d] = zf; acc1[d] = zf; }
    float mi0 = -INFINITY, li0 = 0.f;
    float mi1 = -INFINITY, li1 = 0.f;

    const u16* Kbh = K_ + (size_t)bh * SEQ * HD;
    const u16* Vbh = Vt + (size_t)bh * HD * SEQ;
    const int row = t >> 3, c8 = (t & 7) * 8;

    {
        int4 kr = *(const int4*)(Kbh + (size_t)row * HD + c8);
        int4 vr = *(const int4*)(Vbh + (size_t)row * SEQ + c8);
        *(int4*)&Ks[0][row][c8] = kr;
        *(int4*)&Vs[0][row][c8] = vr;
    }
    __syncthreads();

    for (int jt = 0; jt <= jmax; ++jt) {
        const int cur = jt & 1;
        const int j0 = jt << 6;
        int4 kn, vn;
        if (jt < jmax) {
            int j1 = j0 + 64;
            kn = *(const int4*)(Kbh + (size_t)(j1 + row) * HD + c8);
            vn = *(const int4*)(Vbh + (size_t)row * SEQ + j1 + c8);
        }
        if (j0 <= wrow0 + 31) {
            const u16 (*Kc)[72] = Ks[cur];
            const u16 (*Vc)[72] = Vs[cur];
            f32x4 s0[4], s1[4];
            __builtin_amdgcn_s_setprio(1);
            #pragma unroll
            for (int nt = 0; nt < 4; ++nt) {
                bf16x8 kf0 = *(const bf16x8*)&Kc[nt * 16 + l15][lg * 8];
                bf16x8 kf1 = *(const bf16x8*)&Kc[nt * 16 + l15][32 + lg * 8];
                f32x4 a = zf;
                a = __builtin_amdgcn_mfma_f32_16x16x32_bf16(kf0, qf00, a, 0, 0, 0);
                a = __builtin_amdgcn_mfma_f32_16x16x32_bf16(kf1, qf01, a, 0, 0, 0);
                s0[nt] = a;
                f32x4 c2 = zf;
                c2 = __builtin_amdgcn_mfma_f32_16x16x32_bf16(kf0, qf10, c2, 0, 0, 0);
                c2 = __builtin_amdgcn_mfma_f32_16x16x32_bf16(kf1, qf11, c2, 0, 0, 0);
                s1[nt] = c2;
            }
            __builtin_amdgcn_s_setprio(0);
            if (j0 + 63 > wrow0) {
                #pragma unroll
                for (int nt = 0; nt < 4; ++nt) {
                    int kb = j0 + nt * 16 + lg * 4;
                    #pragma unroll
                    for (int r = 0; r < 4; ++r) {
                        if (kb + r > wrow0 + l15)      s0[nt][r] = -INFINITY;
                        if (kb + r > wrow0 + 16 + l15) s1[nt][r] = -INFINITY;
                    }
                }
            }
            float pm0 = fmaxf(fmaxf(vmax4(s0[0]), vmax4(s0[1])), fmaxf(vmax4(s0[2]), vmax4(s0[3])));
            float pm1 = fmaxf(fmaxf(vmax4(s1[0]), vmax4(s1[1])), fmaxf(vmax4(s1[2]), vmax4(s1[3])));
            pm0 = fmaxf(pm0, __shfl_xor(pm0, 16)); pm0 = fmaxf(pm0, __shfl_xor(pm0, 32));
            pm1 = fmaxf(pm1, __shfl_xor(pm1, 16)); pm1 = fmaxf(pm1, __shfl_xor(pm1, 32));
            if (!__all((pm0 <= mi0 + 8.f) && (pm1 <= mi1 + 8.f))) {
                float mn0 = fmaxf(mi0, pm0), mn1 = fmaxf(mi1, pm1);
                float so0 = __builtin_amdgcn_exp2f(mi0 - mn0);
                float so1 = __builtin_amdgcn_exp2f(mi1 - mn1);
                mi0 = mn0; mi1 = mn1;
                li0 *= so0; li1 *= so1;
                float a0 = __shfl(so0, lg * 4 + 0), a1 = __shfl(so0, lg * 4 + 1);
                float a2 = __shfl(so0, lg * 4 + 2), a3 = __shfl(so0, lg * 4 + 3);
                float b0_ = __shfl(so1, lg * 4 + 0), b1_ = __shfl(so1, lg * 4 + 1);
                float b2_ = __shfl(so1, lg * 4 + 2), b3_ = __shfl(so1, lg * 4 + 3);
                #pragma unroll
                for (int d = 0; d < 4; ++d) {
                    acc0[d][0] *= a0;  acc0[d][1] *= a1;  acc0[d][2] *= a2;  acc0[d][3] *= a3;
                    acc1[d][0] *= b0_; acc1[d][1] *= b1_; acc1[d][2] *= b2_; acc1[d][3] *= b3_;
                }
            }
            u32 dwa[8], dwb[8];
            float rs0 = 0.f, rs1 = 0.f;
            #pragma unroll
            for (int nt = 0; nt < 4; ++nt) {
                float p0 = __builtin_amdgcn_exp2f(s0[nt][0] - mi0);
                float p1 = __builtin_amdgcn_exp2f(s0[nt][1] - mi0);
                float p2 = __builtin_amdgcn_exp2f(s0[nt][2] - mi0);
                float p3 = __builtin_amdgcn_exp2f(s0[nt][3] - mi0);
                rs0 += (p0 + p1) + (p2 + p3);
                dwa[nt * 2] = pkbf(p0, p1); dwa[nt * 2 + 1] = pkbf(p2, p3);
                float q0 = __builtin_amdgcn_exp2f(s1[nt][0] - mi1);
                float q1 = __builtin_amdgcn_exp2f(s1[nt][1] - mi1);
                float q2 = __builtin_amdgcn_exp2f(s1[nt][2] - mi1);
                float q3 = __builtin_amdgcn_exp2f(s1[nt][3] - mi1);
                rs1 += (q0 + q1) + (q2 + q3);
                dwb[nt * 2] = pkbf(q0, q1); dwb[nt * 2 + 1] = pkbf(q2, q3);
            }
            rs0 += __shfl_xor(rs0, 16); rs0 += __shfl_xor(rs0, 32);
            rs1 += __shfl_xor(rs1, 16); rs1 += __shfl_xor(rs1, 32);
            li0 += rs0; li1 += rs1;
            bf16x8 pa00 = __builtin_bit_cast(bf16x8, make_int4((int)dwa[0], (int)dwa[1], (int)dwa[2], (int)dwa[3]));
            bf16x8 pa01 = __builtin_bit_cast(bf16x8, make_int4((int)dwa[4], (int)dwa[5], (int)dwa[6], (int)dwa[7]));
            bf16x8 pa10 = __builtin_bit_cast(bf16x8, make_int4((int)dwb[0], (int)dwb[1], (int)dwb[2], (int)dwb[3]));
            bf16x8 pa11 = __builtin_bit_cast(bf16x8, make_int4((int)dwb[4], (int)dwb[5], (int)dwb[6], (int)dwb[7]));
            __builtin_amdgcn_s_setprio(1);
            #pragma unroll
            for (int d = 0; d < 4; ++d) {
                const u16* vrow = Vc[d * 16 + l15];
                int2 v0 = *(const int2*)(vrow + lg * 4);
                int2 v1 = *(const int2*)(vrow + 16 + lg * 4);
                int2 v2 = *(const int2*)(vrow + 32 + lg * 4);
                int2 v3 = *(const int2*)(vrow + 48 + lg * 4);
                bf16x8 vf0 = __builtin_bit_cast(bf16x8, make_int4(v0.x, v0.y, v1.x, v1.y));
                bf16x8 vf1 = __builtin_bit_cast(bf16x8, make_int4(v2.x, v2.y, v3.x, v3.y));
                acc0[d] = __builtin_amdgcn_mfma_f32_16x16x32_bf16(pa00, vf0, acc0[d], 0, 0, 0);
                acc0[d] = __builtin_amdgcn_mfma_f32_16x16x32_bf16(pa01, vf1, acc0[d], 0, 0, 0);
                acc1[d] = __builtin_amdgcn_mfma_f32_16x16x32_bf16(pa10, vf0, acc1[d], 0, 0, 0);
                acc1[d] = __builtin_amdgcn_mfma_f32_16x16x32_bf16(pa11, vf1, acc1[d], 0, 0, 0);
            }
            __builtin_amdgcn_s_setprio(0);
        }
        if (jt < jmax) {
            *(int4*)&Ks[cur ^ 1][row][c8] = kn;
            *(int4*)&Vs[cur ^ 1][row][c8] = vn;
        }
        __syncthreads();
    }

    float e00 = 1.0f / __shfl(li0, lg * 4 + 0), e01 = 1.0f / __shfl(li0, lg * 4 + 1);
    float e02 = 1.0f / __shfl(li0, lg * 4 + 2), e03 = 1.0f / __shfl(li0, lg * 4 + 3);
    float e10 = 1.0f / __shfl(li1, lg * 4 + 0), e11 = 1.0f / __shfl(li1, lg * 4 + 1);
    float e12 = 1.0f / __shfl(li1, lg * 4 + 2), e13 = 1.0f / __shfl(li1, lg * 4 + 3);
    #pragma unroll
    for (int r = 0; r < 4; ++r) {
        float f0 = (r == 0) ? e00 : (r == 1) ? e01 : (r == 2) ? e02 : e03;
        float f1 = (r == 0) ? e10 : (r == 1) ? e11 : (r == 2) ? e12 : e13;
        int s0r = wrow0 + lg * 4 + r;
        size_t base0 = ((size_t)b * SEQ + s0r) * DM + h * HD;
        size_t base1 = ((size_t)b * SEQ + s0r + 16) * DM + h * HD;
        #pragma unroll
        for (int d = 0; d < 4; ++d) {
            ctx[base0 + d * 16 + l15] = f2bf(acc0[d][r] * f0);
            ctx[base1 + d * 16 + l15] = f2bf(acc1[d][r] * f1);
        }
    }
}

extern "C" void kernel_launch(void* const* d_in, const int* in_sizes, int n_in,
                              void* d_out, int out_size, void* d_ws, size_t ws_size,
                              hipStream_t stream) {
    const float* x  = (const float*)d_in[0];
    const float* Wq = (const float*)d_in[1];
    const float* bq = (const float*)d_in[2];
    const float* Wk = (const float*)d_in[3];
    const float* bk = (const float*)d_in[4];
    const float* Wv = (const float*)d_in[5];
    const float* bv = (const float*)d_in[6];
    const float* Wo = (const float*)d_in[7];
    const float* bo = (const float*)d_in[8];
    float* out = (float*)d_out;

    char* ws = (char*)d_ws;
    u16* xb  = (u16*)(ws);                    // 8192*768*2      = 12,582,912
    u16* Wt  = (u16*)(ws + 12582912);         // 2304*768*2      =  3,538,944
    u16* Wto = (u16*)(ws + 16121856);         // 768*768*2       =  1,179,648
    u16* Qw  = (u16*)(ws + 17301504);         // [BH][S][64]     = 12,582,912
    u16* Kw  = (u16*)(ws + 29884416);         // [BH][S][64]     = 12,582,912
    u16* Vtw = (u16*)(ws + 42467328);         // [BH][64][S]     = 12,582,912
    u16* ctx = (u16*)(ws + 55050240);         // [B][S][768]     = 12,582,912

    cvt_x<<<6144, 256, 0, stream>>>(x, xb, NTOK * DM / 4);
    dim3 tb(32, 8), tg4(24, 24, 4);
    transpose_w4<<<tg4, tb, 0, stream>>>(Wq, Wk, Wv, Wo, Wt, Wto);

    dim3 g2(32, 8);
    gemm_pipe<0><<<g2, 512, 0, stream>>>(xb, Wt, bq, bk, bv, Qw, Kw, Vtw, nullptr);
    attn_fwd<<<384, 512, 0, stream>>>(Qw, Kw, Vtw, ctx);
    dim3 g4(64, 4);
    gemm_pipe<1><<<g4, 512, 0, stream>>>(ctx, Wto, bo, nullptr, nullptr, nullptr, nullptr, nullptr, out);
}